// Round 1
// baseline (7315.401 us; speedup 1.0000x reference)
//
#include <hip/hip_runtime.h>

#define EPS 1e-3f

__device__ __forceinline__ float sigm(float x){ return 1.0f/(1.0f + __expf(-x)); }
__device__ __forceinline__ float tanhfast(float x){ return 1.0f - 2.0f/(1.0f + __expf(2.0f*x)); }

// ---------------- conv(K) + bias + relu + BN + maxpool2 -> concat slice ----------------
__global__ void conv_block_kernel(const float* __restrict__ x,   // [512,256,78]
                                  const float* __restrict__ w,   // [K,78,64]
                                  const float* __restrict__ bias,
                                  const float* __restrict__ bng,
                                  const float* __restrict__ bnb,
                                  const float* __restrict__ bnm,
                                  const float* __restrict__ bnv,
                                  float* __restrict__ out,       // [512,128,192]
                                  int K, int cbase)
{
    int b = blockIdx.x;
    int co = threadIdx.x;                                   // 0..63
    int t_out = blockIdx.y * blockDim.y + threadIdx.y;      // 0..127
    int pad = K >> 1;
    float s  = bng[co] * rsqrtf(bnv[co] + EPS);
    float sh = bnb[co] - bnm[co] * s;
    float best = -1e30f;
    for (int tt = 0; tt < 2; ++tt){
        int tbase = 2*t_out + tt - pad;
        float acc = bias[co];
        for (int k = 0; k < K; ++k){
            int ti = tbase + k;
            if (ti < 0 || ti >= 256) continue;
            const float* xp = x + (b*256 + ti)*78;
            const float* wp = w + (k*78)*64 + co;
            #pragma unroll 6
            for (int ci = 0; ci < 78; ++ci)
                acc = fmaf(xp[ci], wp[ci*64], acc);
        }
        acc = fmaxf(acc, 0.0f) * s + sh;   // relu then BN
        best = fmaxf(best, acc);
    }
    out[(b*128 + t_out)*192 + cbase + co] = best;
}

// ---------------- 1x1 fuse conv: [65536,192]@[192,128]+b ----------------
__global__ void fuse_kernel(const float* __restrict__ in,
                            const float* __restrict__ w,
                            const float* __restrict__ bias,
                            float* __restrict__ out)
{
    int row = blockIdx.x * blockDim.y + threadIdx.y;
    int co  = threadIdx.x;                 // 0..127
    const float* ip = in + (size_t)row*192;
    float acc = bias[co];
    #pragma unroll 8
    for (int ci = 0; ci < 192; ++ci)
        acc = fmaf(ip[ci], w[ci*128 + co], acc);
    out[(size_t)row*128 + co] = acc;
}

// ---------------- SE: mean over T, 128->8 relu, 8->128 sigmoid, scale in place ----------------
__global__ void se_kernel(float* __restrict__ fused,           // [512,128,128]
                          const float* __restrict__ w1, const float* __restrict__ b1,
                          const float* __restrict__ w2, const float* __restrict__ b2)
{
    int b = blockIdx.x, c = threadIdx.x;   // 128 threads
    __shared__ float sv[128];
    __shared__ float rv[8];
    float* fp = fused + (size_t)b*128*128 + c;
    float acc = 0.f;
    for (int t = 0; t < 128; ++t) acc += fp[t*128];
    sv[c] = acc * (1.f/128.f);
    __syncthreads();
    if (c < 8){
        float r = b1[c];
        for (int i = 0; i < 128; ++i) r = fmaf(sv[i], w1[i*8 + c], r);
        rv[c] = fmaxf(r, 0.f);
    }
    __syncthreads();
    float e = b2[c];
    #pragma unroll
    for (int j = 0; j < 8; ++j) e = fmaf(rv[j], w2[j*128 + c], e);
    e = sigm(e);
    for (int t = 0; t < 128; ++t) fp[t*128] *= e;
}

// ---------------- BiLSTM layer 1: in 128, units 128, z=512. BN(bn_l1) folded into write ----------------
#define RB1 4
__global__ void __launch_bounds__(1024)
lstm1_kernel(const float* __restrict__ xin,  // [512,128,128]
             const float* __restrict__ Kf, const float* __restrict__ Rf, const float* __restrict__ bf,
             const float* __restrict__ Kb, const float* __restrict__ Rb, const float* __restrict__ bb,
             const float* __restrict__ bng, const float* __restrict__ bnb,
             const float* __restrict__ bnm, const float* __restrict__ bnv,
             float* __restrict__ out)        // [512,128,256]
{
    const int dir = blockIdx.y;
    const int b0  = blockIdx.x * RB1;
    const float* Kw = dir ? Kb : Kf;
    const float* Rw = dir ? Rb : Rf;
    const float* bw = dir ? bb : bf;

    __shared__ float xl[RB1][128];
    __shared__ float hl[RB1][128];
    __shared__ float cl[RB1][128];
    __shared__ float zl[RB1][512];

    int tid = threadIdx.x;
    for (int idx = tid; idx < RB1*128; idx += blockDim.x){
        ((float*)hl)[idx] = 0.f;
        ((float*)cl)[idx] = 0.f;
    }
    const int j  = tid & 511;
    const int pr = tid >> 9;          // 0/1 -> batch rows pr*2, pr*2+1
    const float bj = bw[j];
    const int u   = tid & 127;
    const int grb = (tid >> 7) & 3;
    const int ch  = dir ? 128 + u : u;
    const float bns  = bng[ch] * rsqrtf(bnv[ch] + EPS);
    const float bnsh = bnb[ch] - bnm[ch] * bns;
    __syncthreads();

    for (int ts = 0; ts < 128; ++ts){
        int t = dir ? 127 - ts : ts;
        if (tid < RB1*128){
            int rb = tid >> 7, i = tid & 127;
            xl[rb][i] = xin[((size_t)(b0+rb)*128 + t)*128 + i];
        }
        __syncthreads();
        {
            int r0 = pr*2, r1 = pr*2 + 1;
            float a0 = bj, a1 = bj;
            #pragma unroll 4
            for (int i = 0; i < 128; ++i){
                float kv = Kw[i*512 + j];
                float rv = Rw[i*512 + j];
                a0 = fmaf(xl[r0][i], kv, a0);
                a0 = fmaf(hl[r0][i], rv, a0);
                a1 = fmaf(xl[r1][i], kv, a1);
                a1 = fmaf(hl[r1][i], rv, a1);
            }
            zl[r0][j] = a0;
            zl[r1][j] = a1;
        }
        __syncthreads();
        if (tid < RB1*128){
            float iv = sigm(zl[grb][u]);
            float fv = sigm(zl[grb][u + 128]);
            float gv = tanhfast(zl[grb][u + 256]);
            float ov = sigm(zl[grb][u + 384]);
            float c  = fv * cl[grb][u] + iv * gv;
            cl[grb][u] = c;
            float h = ov * tanhfast(c);
            hl[grb][u] = h;
            out[((size_t)(b0+grb)*128 + t)*256 + ch] = fmaf(h, bns, bnsh);
        }
        __syncthreads();
    }
}

// ---------------- BiLSTM layer 2: in 256, units 64, z=256. BN(bn_l2) folded ----------------
#define RB2 4
__global__ void __launch_bounds__(512)
lstm2_kernel(const float* __restrict__ xin,  // [512,128,256]
             const float* __restrict__ Kf, const float* __restrict__ Rf, const float* __restrict__ bf,
             const float* __restrict__ Kb, const float* __restrict__ Rb, const float* __restrict__ bb,
             const float* __restrict__ bng, const float* __restrict__ bnb,
             const float* __restrict__ bnm, const float* __restrict__ bnv,
             float* __restrict__ out)        // [512,128,128]
{
    const int dir = blockIdx.y;
    const int b0  = blockIdx.x * RB2;
    const float* Kw = dir ? Kb : Kf;
    const float* Rw = dir ? Rb : Rf;
    const float* bw = dir ? bb : bf;

    __shared__ float xl[RB2][256];
    __shared__ float hl[RB2][64];
    __shared__ float cl[RB2][64];
    __shared__ float zl[RB2][256];

    int tid = threadIdx.x;
    for (int idx = tid; idx < RB2*64; idx += blockDim.x){
        ((float*)hl)[idx] = 0.f;
        ((float*)cl)[idx] = 0.f;
    }
    const int j  = tid & 255;
    const int pr = tid >> 8;
    const float bj = bw[j];
    const int u   = tid & 63;
    const int grb = (tid >> 6) & 3;
    const int ch  = dir ? 64 + u : u;
    const float bns  = bng[ch] * rsqrtf(bnv[ch] + EPS);
    const float bnsh = bnb[ch] - bnm[ch] * bns;
    __syncthreads();

    for (int ts = 0; ts < 128; ++ts){
        int t = dir ? 127 - ts : ts;
        for (int idx = tid; idx < RB2*256; idx += 512){
            int rb = idx >> 8, i = idx & 255;
            xl[rb][i] = xin[((size_t)(b0+rb)*128 + t)*256 + i];
        }
        __syncthreads();
        {
            int r0 = pr*2, r1 = pr*2 + 1;
            float a0 = bj, a1 = bj;
            #pragma unroll 4
            for (int i = 0; i < 256; ++i){
                float kv = Kw[i*256 + j];
                a0 = fmaf(xl[r0][i], kv, a0);
                a1 = fmaf(xl[r1][i], kv, a1);
            }
            #pragma unroll 4
            for (int i = 0; i < 64; ++i){
                float rv = Rw[i*256 + j];
                a0 = fmaf(hl[r0][i], rv, a0);
                a1 = fmaf(hl[r1][i], rv, a1);
            }
            zl[r0][j] = a0;
            zl[r1][j] = a1;
        }
        __syncthreads();
        if (tid < RB2*64){
            float iv = sigm(zl[grb][u]);
            float fv = sigm(zl[grb][u + 64]);
            float gv = tanhfast(zl[grb][u + 128]);
            float ov = sigm(zl[grb][u + 192]);
            float c  = fv * cl[grb][u] + iv * gv;
            cl[grb][u] = c;
            float h = ov * tanhfast(c);
            hl[grb][u] = h;
            out[((size_t)(b0+grb)*128 + t)*128 + ch] = fmaf(h, bns, bnsh);
        }
        __syncthreads();
    }
}

// ---------------- MHSA per (b, head): qkv proj + flash softmax + T-mean ----------------
__global__ void __launch_bounds__(128)
mhsa_kernel(const float* __restrict__ h2,    // [512,128,128]
            const float* __restrict__ wq, const float* __restrict__ bq,
            const float* __restrict__ wk, const float* __restrict__ bk,
            const float* __restrict__ wv, const float* __restrict__ bv,
            float* __restrict__ msum)        // [512,256] = mean_t(attn out)
{
    int b = blockIdx.x, hd = blockIdx.y, t = threadIdx.x;  // t: 0..127
    int cb = hd * 32;
    __shared__ float kx[128][33];
    __shared__ float vx[128][33];
    __shared__ float red[128][33];

    float q[32], kk[32], vv[32];
    #pragma unroll
    for (int d = 0; d < 32; ++d){ q[d] = bq[cb+d]; kk[d] = bk[cb+d]; vv[d] = bv[cb+d]; }
    const float* xr = h2 + ((size_t)b*128 + t)*128;
    for (int i = 0; i < 128; ++i){
        float xv = xr[i];
        const float* wqp = wq + i*256 + cb;
        const float* wkp = wk + i*256 + cb;
        const float* wvp = wv + i*256 + cb;
        #pragma unroll
        for (int d = 0; d < 32; ++d){
            q[d]  = fmaf(xv, wqp[d], q[d]);
            kk[d] = fmaf(xv, wkp[d], kk[d]);
            vv[d] = fmaf(xv, wvp[d], vv[d]);
        }
    }
    #pragma unroll
    for (int d = 0; d < 32; ++d){ kx[t][d] = kk[d]; vx[t][d] = vv[d]; }
    __syncthreads();

    float m = -1e30f, l = 0.f, acc[32];
    #pragma unroll
    for (int d = 0; d < 32; ++d) acc[d] = 0.f;
    const float scale = 0.17677669529663687f;   // 1/sqrt(32)
    for (int tp = 0; tp < 128; ++tp){
        float s = 0.f;
        #pragma unroll
        for (int d = 0; d < 32; ++d) s = fmaf(q[d], kx[tp][d], s);
        s *= scale;
        float mn = fmaxf(m, s);
        float corr = __expf(m - mn);
        float p = __expf(s - mn);
        l = l * corr + p;
        #pragma unroll
        for (int d = 0; d < 32; ++d) acc[d] = fmaf(p, vx[tp][d], acc[d]*corr);
        m = mn;
    }
    float inv = 1.f / l;
    #pragma unroll
    for (int d = 0; d < 32; ++d) red[t][d] = acc[d] * inv;
    __syncthreads();
    if (t < 32){
        float s = 0.f;
        for (int i = 0; i < 128; ++i) s += red[i][t];
        msum[(size_t)b*256 + cb + t] = s * (1.f/128.f);
    }
}

// ---------------- head: wo proj + d1(relu,bn) + d2(relu,bn) + d3 sigmoid ----------------
__global__ void __launch_bounds__(256)
head_kernel(const float* __restrict__ msum,  // [512,256]
            const float* __restrict__ wo, const float* __restrict__ bo,
            const float* __restrict__ d1w, const float* __restrict__ d1b,
            const float* __restrict__ g1, const float* __restrict__ b1,
            const float* __restrict__ m1, const float* __restrict__ v1,
            const float* __restrict__ d2w, const float* __restrict__ d2b,
            const float* __restrict__ g2, const float* __restrict__ b2,
            const float* __restrict__ m2, const float* __restrict__ v2,
            const float* __restrict__ d3w, const float* __restrict__ d3b,
            float* __restrict__ outp)        // [512]
{
    int b = blockIdx.x, j = threadIdx.x;     // 256 threads
    __shared__ float s1[256];
    __shared__ float s2[256];
    const float* mr = msum + (size_t)b*256;
    float acc = bo[j];
    #pragma unroll 4
    for (int i = 0; i < 256; ++i) acc = fmaf(mr[i], wo[i*256 + j], acc);
    s1[j] = acc;
    __syncthreads();
    float a1 = d1b[j];
    #pragma unroll 4
    for (int i = 0; i < 256; ++i) a1 = fmaf(s1[i], d1w[i*256 + j], a1);
    a1 = fmaxf(a1, 0.f);
    float sc1 = g1[j] * rsqrtf(v1[j] + EPS);
    a1 = a1 * sc1 + (b1[j] - m1[j] * sc1);
    s2[j] = a1;
    __syncthreads();
    if (j < 128){
        float a2 = d2b[j];
        #pragma unroll 4
        for (int i = 0; i < 256; ++i) a2 = fmaf(s2[i], d2w[i*128 + j], a2);
        a2 = fmaxf(a2, 0.f);
        float sc2 = g2[j] * rsqrtf(v2[j] + EPS);
        a2 = a2 * sc2 + (b2[j] - m2[j] * sc2);
        s1[j] = a2;
    }
    __syncthreads();
    if (j == 0){
        float a3 = d3b[0];
        for (int i = 0; i < 128; ++i) a3 = fmaf(s1[i], d3w[i], a3);
        outp[b] = sigm(a3);
    }
}

extern "C" void kernel_launch(void* const* d_in, const int* in_sizes, int n_in,
                              void* d_out, int out_size, void* d_ws, size_t ws_size,
                              hipStream_t stream)
{
    #define F(i) ((const float*)d_in[i])
    const float* x       = F(0);
    const float* conv5_w = F(1);
    const float* conv7_w = F(2);
    const float* conv9_w = F(3);
    const float* fuse_w  = F(4);
    const float* se_w1   = F(5);
    const float* se_w2   = F(6);
    const float* l1f_k   = F(7);
    const float* l1f_r   = F(8);
    const float* l1b_k   = F(9);
    const float* l1b_r   = F(10);
    const float* l2f_k   = F(11);
    const float* l2f_r   = F(12);
    const float* l2b_k   = F(13);
    const float* l2b_r   = F(14);
    const float* wq      = F(15);
    const float* wk      = F(16);
    const float* wv      = F(17);
    const float* wo      = F(18);
    const float* d1_w    = F(19);
    const float* d2_w    = F(20);
    const float* d3_w    = F(21);
    const float* conv5_b = F(22);
    const float* conv7_b = F(23);
    const float* conv9_b = F(24);
    const float* fuse_b  = F(25);
    const float* se_b1   = F(26);
    const float* se_b2   = F(27);
    const float* l1f_b   = F(28);
    const float* l1b_b   = F(29);
    const float* l2f_b   = F(30);
    const float* l2b_b   = F(31);
    const float* bq      = F(32);
    const float* bk      = F(33);
    const float* bv      = F(34);
    const float* bo      = F(35);
    const float* d1_b    = F(36);
    const float* d2_b    = F(37);
    const float* d3_b    = F(38);
    const float* bn5_g = F(39), *bn5_b = F(40), *bn5_m = F(41), *bn5_v = F(42);
    const float* bn7_g = F(43), *bn7_b = F(44), *bn7_m = F(45), *bn7_v = F(46);
    const float* bn9_g = F(47), *bn9_b = F(48), *bn9_m = F(49), *bn9_v = F(50);
    const float* bnl1_g = F(51), *bnl1_b = F(52), *bnl1_m = F(53), *bnl1_v = F(54);
    const float* bnl2_g = F(55), *bnl2_b = F(56), *bnl2_m = F(57), *bnl2_v = F(58);
    const float* bnd1_g = F(59), *bnd1_b = F(60), *bnd1_m = F(61), *bnd1_v = F(62);
    const float* bnd2_g = F(63), *bnd2_b = F(64), *bnd2_m = F(65), *bnd2_v = F(66);
    #undef F

    float* ws = (float*)d_ws;
    float* concat = ws;                         // 512*128*192 = 12,582,912 floats
    float* fused  = concat + 12582912;          // 512*128*128 =  8,388,608
    float* l1out  = fused + 8388608;            // 512*128*256 = 16,777,216
    float* l2out  = concat;                     // reuse concat region (needs 8,388,608)
    float* msum   = fused;                      // reuse fused region (needs 131,072)
    float* outp   = (float*)d_out;

    // conv blocks
    conv_block_kernel<<<dim3(512,32), dim3(64,4), 0, stream>>>(
        x, conv5_w, conv5_b, bn5_g, bn5_b, bn5_m, bn5_v, concat, 5, 0);
    conv_block_kernel<<<dim3(512,32), dim3(64,4), 0, stream>>>(
        x, conv7_w, conv7_b, bn7_g, bn7_b, bn7_m, bn7_v, concat, 7, 64);
    conv_block_kernel<<<dim3(512,32), dim3(64,4), 0, stream>>>(
        x, conv9_w, conv9_b, bn9_g, bn9_b, bn9_m, bn9_v, concat, 9, 128);

    // 1x1 fuse
    fuse_kernel<<<dim3(16384), dim3(128,4), 0, stream>>>(concat, fuse_w, fuse_b, fused);

    // SE (in place)
    se_kernel<<<dim3(512), dim3(128), 0, stream>>>(fused, se_w1, se_b1, se_w2, se_b2);

    // BiLSTM 1 (+bn_l1)
    lstm1_kernel<<<dim3(128,2), dim3(1024), 0, stream>>>(
        fused, l1f_k, l1f_r, l1f_b, l1b_k, l1b_r, l1b_b,
        bnl1_g, bnl1_b, bnl1_m, bnl1_v, l1out);

    // BiLSTM 2 (+bn_l2)
    lstm2_kernel<<<dim3(128,2), dim3(512), 0, stream>>>(
        l1out, l2f_k, l2f_r, l2f_b, l2b_k, l2b_r, l2b_b,
        bnl2_g, bnl2_b, bnl2_m, bnl2_v, l2out);

    // MHSA -> per-channel T-mean
    mhsa_kernel<<<dim3(512,8), dim3(128), 0, stream>>>(
        l2out, wq, bq, wk, bk, wv, bv, msum);

    // wo + dense head
    head_kernel<<<dim3(512), dim3(256), 0, stream>>>(
        msum, wo, bo,
        d1_w, d1_b, bnd1_g, bnd1_b, bnd1_m, bnd1_v,
        d2_w, d2_b, bnd2_g, bnd2_b, bnd2_m, bnd2_v,
        d3_w, d3_b, outp);

    (void)in_sizes; (void)n_in; (void)out_size; (void)ws_size;
}

// Round 2
// 3862.632 us; speedup vs baseline: 1.8939x; 1.8939x over previous
//
#include <hip/hip_runtime.h>

#define EPS 1e-3f

__device__ __forceinline__ float sigm(float x){ return 1.0f/(1.0f + __expf(-x)); }
__device__ __forceinline__ float tanhfast(float x){ return 1.0f - 2.0f/(1.0f + __expf(2.0f*x)); }

// ---------------- conv(K) + bias + relu + BN + maxpool2 -> concat slice (v2, register-tiled) ----------------
// Grid: (512 b, 4 tau-tiles of 64). Block: 256 threads.
// Thread: 4 tau x 4 co accumulators. x tile transposed in LDS [ci][u], u = tau - tile*64 + 4.
template<int K>
__global__ void __launch_bounds__(256)
conv_block_v2(const float* __restrict__ x,   // [512,256,78]
              const float* __restrict__ w,   // [K,78,64]
              const float* __restrict__ bias,
              const float* __restrict__ bng,
              const float* __restrict__ bnb,
              const float* __restrict__ bnm,
              const float* __restrict__ bnv,
              float* __restrict__ out,       // [512,128,192]
              int cbase)
{
    constexpr int PAD = K / 2;
    constexpr int OFF = 4 - PAD;          // xv[q] = xt[ci][tg*4 + OFF + q]
    constexpr int NX  = 3 + K;            // xv size

    __shared__ float xt[78][73];          // u: 0..71 -> t = tile*64 - 4 + u; stride 73 (bank-spread)

    const int b    = blockIdx.x;
    const int tile = blockIdx.y;
    const int tid  = threadIdx.x;
    const int tbase = tile*64 - 4;

    for (int idx = tid; idx < 72*78; idx += 256){
        int u  = idx / 78;
        int ci = idx - u*78;
        int t  = tbase + u;
        xt[ci][u] = (t >= 0 && t < 256) ? x[((size_t)b*256 + t)*78 + ci] : 0.f;
    }
    __syncthreads();

    const int cog = tid & 15;
    const int tg  = tid >> 4;             // 0..15 -> 4 tau each
    const int co  = cog * 4;

    float acc[4][4];
    {
        const float4 b4 = *(const float4*)(bias + co);
        #pragma unroll
        for (int r = 0; r < 4; ++r){
            acc[r][0] = b4.x; acc[r][1] = b4.y; acc[r][2] = b4.z; acc[r][3] = b4.w;
        }
    }

    for (int ci = 0; ci < 78; ++ci){
        float xv[NX];
        #pragma unroll
        for (int q = 0; q < NX; ++q) xv[q] = xt[ci][tg*4 + OFF + q];
        #pragma unroll
        for (int k = 0; k < K; ++k){
            const float4 wv = *(const float4*)(w + ((size_t)(k*78 + ci))*64 + co);
            #pragma unroll
            for (int r = 0; r < 4; ++r){
                acc[r][0] = fmaf(xv[r+k], wv.x, acc[r][0]);
                acc[r][1] = fmaf(xv[r+k], wv.y, acc[r][1]);
                acc[r][2] = fmaf(xv[r+k], wv.z, acc[r][2]);
                acc[r][3] = fmaf(xv[r+k], wv.w, acc[r][3]);
            }
        }
    }

    // relu -> BN -> maxpool(2)
    float s[4], sh[4];
    #pragma unroll
    for (int c = 0; c < 4; ++c){
        s[c]  = bng[co+c] * rsqrtf(bnv[co+c] + EPS);
        sh[c] = bnb[co+c] - bnm[co+c] * s[c];
    }
    #pragma unroll
    for (int pr = 0; pr < 2; ++pr){
        float4 o;
        float v0, v1;
        v0 = fmaxf(acc[2*pr][0],0.f)*s[0]+sh[0]; v1 = fmaxf(acc[2*pr+1][0],0.f)*s[0]+sh[0]; o.x = fmaxf(v0,v1);
        v0 = fmaxf(acc[2*pr][1],0.f)*s[1]+sh[1]; v1 = fmaxf(acc[2*pr+1][1],0.f)*s[1]+sh[1]; o.y = fmaxf(v0,v1);
        v0 = fmaxf(acc[2*pr][2],0.f)*s[2]+sh[2]; v1 = fmaxf(acc[2*pr+1][2],0.f)*s[2]+sh[2]; o.z = fmaxf(v0,v1);
        v0 = fmaxf(acc[2*pr][3],0.f)*s[3]+sh[3]; v1 = fmaxf(acc[2*pr+1][3],0.f)*s[3]+sh[3]; o.w = fmaxf(v0,v1);
        int t_out = tile*32 + tg*2 + pr;
        *(float4*)(out + ((size_t)b*128 + t_out)*192 + cbase + co) = o;
    }
}

// ---------------- 1x1 fuse conv: [65536,192]@[192,128]+b (v2, 8-row tiled) ----------------
__global__ void __launch_bounds__(256)
fuse_v2(const float* __restrict__ in,
        const float* __restrict__ w,
        const float* __restrict__ bias,
        float* __restrict__ out)
{
    __shared__ float xl[16][192];
    const int tid = threadIdx.x;
    const size_t row0 = (size_t)blockIdx.x * 16;

    {
        const float4* ip = (const float4*)(in + row0*192);
        float4* xp = (float4*)&xl[0][0];
        #pragma unroll
        for (int idx = tid; idx < 768; idx += 256) xp[idx] = ip[idx];
    }
    __syncthreads();

    const int co = tid & 127;
    const int rg = tid >> 7;              // rows rg*8 .. rg*8+7
    float acc[8];
    {
        float bv = bias[co];
        #pragma unroll
        for (int r = 0; r < 8; ++r) acc[r] = bv;
    }

    for (int ci4 = 0; ci4 < 192; ci4 += 4){
        float wv0 = w[(ci4+0)*128 + co];
        float wv1 = w[(ci4+1)*128 + co];
        float wv2 = w[(ci4+2)*128 + co];
        float wv3 = w[(ci4+3)*128 + co];
        #pragma unroll
        for (int r = 0; r < 8; ++r){
            const float4 xr = *(const float4*)&xl[rg*8 + r][ci4];
            acc[r] = fmaf(xr.x, wv0, acc[r]);
            acc[r] = fmaf(xr.y, wv1, acc[r]);
            acc[r] = fmaf(xr.z, wv2, acc[r]);
            acc[r] = fmaf(xr.w, wv3, acc[r]);
        }
    }
    #pragma unroll
    for (int r = 0; r < 8; ++r)
        out[(row0 + rg*8 + r)*128 + co] = acc[r];
}

// ---------------- SE: mean over T, 128->8 relu, 8->128 sigmoid, scale in place ----------------
__global__ void se_kernel(float* __restrict__ fused,           // [512,128,128]
                          const float* __restrict__ w1, const float* __restrict__ b1,
                          const float* __restrict__ w2, const float* __restrict__ b2)
{
    int b = blockIdx.x, c = threadIdx.x;   // 128 threads
    __shared__ float sv[128];
    __shared__ float rv[8];
    float* fp = fused + (size_t)b*128*128 + c;
    float acc = 0.f;
    for (int t = 0; t < 128; ++t) acc += fp[t*128];
    sv[c] = acc * (1.f/128.f);
    __syncthreads();
    if (c < 8){
        float r = b1[c];
        for (int i = 0; i < 128; ++i) r = fmaf(sv[i], w1[i*8 + c], r);
        rv[c] = fmaxf(r, 0.f);
    }
    __syncthreads();
    float e = b2[c];
    #pragma unroll
    for (int j = 0; j < 8; ++j) e = fmaf(rv[j], w2[j*128 + c], e);
    e = sigm(e);
    for (int t = 0; t < 128; ++t) fp[t*128] *= e;
}

// ---------------- BiLSTM layer 1: in 128, units 128, z=512. BN(bn_l1) folded into write ----------------
#define RB1 4
__global__ void __launch_bounds__(1024)
lstm1_kernel(const float* __restrict__ xin,  // [512,128,128]
             const float* __restrict__ Kf, const float* __restrict__ Rf, const float* __restrict__ bf,
             const float* __restrict__ Kb, const float* __restrict__ Rb, const float* __restrict__ bb,
             const float* __restrict__ bng, const float* __restrict__ bnb,
             const float* __restrict__ bnm, const float* __restrict__ bnv,
             float* __restrict__ out)        // [512,128,256]
{
    const int dir = blockIdx.y;
    const int b0  = blockIdx.x * RB1;
    const float* Kw = dir ? Kb : Kf;
    const float* Rw = dir ? Rb : Rf;
    const float* bw = dir ? bb : bf;

    __shared__ float xl[RB1][128];
    __shared__ float hl[RB1][128];
    __shared__ float cl[RB1][128];
    __shared__ float zl[RB1][512];

    int tid = threadIdx.x;
    for (int idx = tid; idx < RB1*128; idx += blockDim.x){
        ((float*)hl)[idx] = 0.f;
        ((float*)cl)[idx] = 0.f;
    }
    const int j  = tid & 511;
    const int pr = tid >> 9;          // 0/1 -> batch rows pr*2, pr*2+1
    const float bj = bw[j];
    const int u   = tid & 127;
    const int grb = (tid >> 7) & 3;
    const int ch  = dir ? 128 + u : u;
    const float bns  = bng[ch] * rsqrtf(bnv[ch] + EPS);
    const float bnsh = bnb[ch] - bnm[ch] * bns;
    __syncthreads();

    for (int ts = 0; ts < 128; ++ts){
        int t = dir ? 127 - ts : ts;
        if (tid < RB1*128){
            int rb = tid >> 7, i = tid & 127;
            xl[rb][i] = xin[((size_t)(b0+rb)*128 + t)*128 + i];
        }
        __syncthreads();
        {
            int r0 = pr*2, r1 = pr*2 + 1;
            float a0 = bj, a1 = bj;
            #pragma unroll 4
            for (int i = 0; i < 128; ++i){
                float kv = Kw[i*512 + j];
                float rv = Rw[i*512 + j];
                a0 = fmaf(xl[r0][i], kv, a0);
                a0 = fmaf(hl[r0][i], rv, a0);
                a1 = fmaf(xl[r1][i], kv, a1);
                a1 = fmaf(hl[r1][i], rv, a1);
            }
            zl[r0][j] = a0;
            zl[r1][j] = a1;
        }
        __syncthreads();
        if (tid < RB1*128){
            float iv = sigm(zl[grb][u]);
            float fv = sigm(zl[grb][u + 128]);
            float gv = tanhfast(zl[grb][u + 256]);
            float ov = sigm(zl[grb][u + 384]);
            float c  = fv * cl[grb][u] + iv * gv;
            cl[grb][u] = c;
            float h = ov * tanhfast(c);
            hl[grb][u] = h;
            out[((size_t)(b0+grb)*128 + t)*256 + ch] = fmaf(h, bns, bnsh);
        }
        __syncthreads();
    }
}

// ---------------- BiLSTM layer 2: in 256, units 64, z=256. BN(bn_l2) folded ----------------
#define RB2 4
__global__ void __launch_bounds__(512)
lstm2_kernel(const float* __restrict__ xin,  // [512,128,256]
             const float* __restrict__ Kf, const float* __restrict__ Rf, const float* __restrict__ bf,
             const float* __restrict__ Kb, const float* __restrict__ Rb, const float* __restrict__ bb,
             const float* __restrict__ bng, const float* __restrict__ bnb,
             const float* __restrict__ bnm, const float* __restrict__ bnv,
             float* __restrict__ out)        // [512,128,128]
{
    const int dir = blockIdx.y;
    const int b0  = blockIdx.x * RB2;
    const float* Kw = dir ? Kb : Kf;
    const float* Rw = dir ? Rb : Rf;
    const float* bw = dir ? bb : bf;

    __shared__ float xl[RB2][256];
    __shared__ float hl[RB2][64];
    __shared__ float cl[RB2][64];
    __shared__ float zl[RB2][256];

    int tid = threadIdx.x;
    for (int idx = tid; idx < RB2*64; idx += blockDim.x){
        ((float*)hl)[idx] = 0.f;
        ((float*)cl)[idx] = 0.f;
    }
    const int j  = tid & 255;
    const int pr = tid >> 8;
    const float bj = bw[j];
    const int u   = tid & 63;
    const int grb = (tid >> 6) & 3;
    const int ch  = dir ? 64 + u : u;
    const float bns  = bng[ch] * rsqrtf(bnv[ch] + EPS);
    const float bnsh = bnb[ch] - bnm[ch] * bns;
    __syncthreads();

    for (int ts = 0; ts < 128; ++ts){
        int t = dir ? 127 - ts : ts;
        for (int idx = tid; idx < RB2*256; idx += 512){
            int rb = idx >> 8, i = idx & 255;
            xl[rb][i] = xin[((size_t)(b0+rb)*128 + t)*256 + i];
        }
        __syncthreads();
        {
            int r0 = pr*2, r1 = pr*2 + 1;
            float a0 = bj, a1 = bj;
            #pragma unroll 4
            for (int i = 0; i < 256; ++i){
                float kv = Kw[i*256 + j];
                a0 = fmaf(xl[r0][i], kv, a0);
                a1 = fmaf(xl[r1][i], kv, a1);
            }
            #pragma unroll 4
            for (int i = 0; i < 64; ++i){
                float rv = Rw[i*256 + j];
                a0 = fmaf(hl[r0][i], rv, a0);
                a1 = fmaf(hl[r1][i], rv, a1);
            }
            zl[r0][j] = a0;
            zl[r1][j] = a1;
        }
        __syncthreads();
        if (tid < RB2*64){
            float iv = sigm(zl[grb][u]);
            float fv = sigm(zl[grb][u + 64]);
            float gv = tanhfast(zl[grb][u + 128]);
            float ov = sigm(zl[grb][u + 192]);
            float c  = fv * cl[grb][u] + iv * gv;
            cl[grb][u] = c;
            float h = ov * tanhfast(c);
            hl[grb][u] = h;
            out[((size_t)(b0+grb)*128 + t)*128 + ch] = fmaf(h, bns, bnsh);
        }
        __syncthreads();
    }
}

// ---------------- MHSA per (b, head): qkv proj + flash softmax + T-mean ----------------
__global__ void __launch_bounds__(128)
mhsa_kernel(const float* __restrict__ h2,    // [512,128,128]
            const float* __restrict__ wq, const float* __restrict__ bq,
            const float* __restrict__ wk, const float* __restrict__ bk,
            const float* __restrict__ wv, const float* __restrict__ bv,
            float* __restrict__ msum)        // [512,256] = mean_t(attn out)
{
    int b = blockIdx.x, hd = blockIdx.y, t = threadIdx.x;  // t: 0..127
    int cb = hd * 32;
    __shared__ float kx[128][33];
    __shared__ float vx[128][33];
    __shared__ float red[128][33];

    float q[32], kk[32], vv[32];
    #pragma unroll
    for (int d = 0; d < 32; ++d){ q[d] = bq[cb+d]; kk[d] = bk[cb+d]; vv[d] = bv[cb+d]; }
    const float* xr = h2 + ((size_t)b*128 + t)*128;
    for (int i = 0; i < 128; ++i){
        float xv = xr[i];
        const float* wqp = wq + i*256 + cb;
        const float* wkp = wk + i*256 + cb;
        const float* wvp = wv + i*256 + cb;
        #pragma unroll
        for (int d = 0; d < 32; ++d){
            q[d]  = fmaf(xv, wqp[d], q[d]);
            kk[d] = fmaf(xv, wkp[d], kk[d]);
            vv[d] = fmaf(xv, wvp[d], vv[d]);
        }
    }
    #pragma unroll
    for (int d = 0; d < 32; ++d){ kx[t][d] = kk[d]; vx[t][d] = vv[d]; }
    __syncthreads();

    float m = -1e30f, l = 0.f, acc[32];
    #pragma unroll
    for (int d = 0; d < 32; ++d) acc[d] = 0.f;
    const float scale = 0.17677669529663687f;   // 1/sqrt(32)
    for (int tp = 0; tp < 128; ++tp){
        float s = 0.f;
        #pragma unroll
        for (int d = 0; d < 32; ++d) s = fmaf(q[d], kx[tp][d], s);
        s *= scale;
        float mn = fmaxf(m, s);
        float corr = __expf(m - mn);
        float p = __expf(s - mn);
        l = l * corr + p;
        #pragma unroll
        for (int d = 0; d < 32; ++d) acc[d] = fmaf(p, vx[tp][d], acc[d]*corr);
        m = mn;
    }
    float inv = 1.f / l;
    #pragma unroll
    for (int d = 0; d < 32; ++d) red[t][d] = acc[d] * inv;
    __syncthreads();
    if (t < 32){
        float s = 0.f;
        for (int i = 0; i < 128; ++i) s += red[i][t];
        msum[(size_t)b*256 + cb + t] = s * (1.f/128.f);
    }
}

// ---------------- head: wo proj + d1(relu,bn) + d2(relu,bn) + d3 sigmoid ----------------
__global__ void __launch_bounds__(256)
head_kernel(const float* __restrict__ msum,  // [512,256]
            const float* __restrict__ wo, const float* __restrict__ bo,
            const float* __restrict__ d1w, const float* __restrict__ d1b,
            const float* __restrict__ g1, const float* __restrict__ b1,
            const float* __restrict__ m1, const float* __restrict__ v1,
            const float* __restrict__ d2w, const float* __restrict__ d2b,
            const float* __restrict__ g2, const float* __restrict__ b2,
            const float* __restrict__ m2, const float* __restrict__ v2,
            const float* __restrict__ d3w, const float* __restrict__ d3b,
            float* __restrict__ outp)        // [512]
{
    int b = blockIdx.x, j = threadIdx.x;     // 256 threads
    __shared__ float s1[256];
    __shared__ float s2[256];
    const float* mr = msum + (size_t)b*256;
    float acc = bo[j];
    #pragma unroll 4
    for (int i = 0; i < 256; ++i) acc = fmaf(mr[i], wo[i*256 + j], acc);
    s1[j] = acc;
    __syncthreads();
    float a1 = d1b[j];
    #pragma unroll 4
    for (int i = 0; i < 256; ++i) a1 = fmaf(s1[i], d1w[i*256 + j], a1);
    a1 = fmaxf(a1, 0.f);
    float sc1 = g1[j] * rsqrtf(v1[j] + EPS);
    a1 = a1 * sc1 + (b1[j] - m1[j] * sc1);
    s2[j] = a1;
    __syncthreads();
    if (j < 128){
        float a2 = d2b[j];
        #pragma unroll 4
        for (int i = 0; i < 256; ++i) a2 = fmaf(s2[i], d2w[i*128 + j], a2);
        a2 = fmaxf(a2, 0.f);
        float sc2 = g2[j] * rsqrtf(v2[j] + EPS);
        a2 = a2 * sc2 + (b2[j] - m2[j] * sc2);
        s1[j] = a2;
    }
    __syncthreads();
    if (j == 0){
        float a3 = d3b[0];
        for (int i = 0; i < 128; ++i) a3 = fmaf(s1[i], d3w[i], a3);
        outp[b] = sigm(a3);
    }
}

extern "C" void kernel_launch(void* const* d_in, const int* in_sizes, int n_in,
                              void* d_out, int out_size, void* d_ws, size_t ws_size,
                              hipStream_t stream)
{
    #define F(i) ((const float*)d_in[i])
    const float* x       = F(0);
    const float* conv5_w = F(1);
    const float* conv7_w = F(2);
    const float* conv9_w = F(3);
    const float* fuse_w  = F(4);
    const float* se_w1   = F(5);
    const float* se_w2   = F(6);
    const float* l1f_k   = F(7);
    const float* l1f_r   = F(8);
    const float* l1b_k   = F(9);
    const float* l1b_r   = F(10);
    const float* l2f_k   = F(11);
    const float* l2f_r   = F(12);
    const float* l2b_k   = F(13);
    const float* l2b_r   = F(14);
    const float* wq      = F(15);
    const float* wk      = F(16);
    const float* wv      = F(17);
    const float* wo      = F(18);
    const float* d1_w    = F(19);
    const float* d2_w    = F(20);
    const float* d3_w    = F(21);
    const float* conv5_b = F(22);
    const float* conv7_b = F(23);
    const float* conv9_b = F(24);
    const float* fuse_b  = F(25);
    const float* se_b1   = F(26);
    const float* se_b2   = F(27);
    const float* l1f_b   = F(28);
    const float* l1b_b   = F(29);
    const float* l2f_b   = F(30);
    const float* l2b_b   = F(31);
    const float* bq      = F(32);
    const float* bk      = F(33);
    const float* bv      = F(34);
    const float* bo      = F(35);
    const float* d1_b    = F(36);
    const float* d2_b    = F(37);
    const float* d3_b    = F(38);
    const float* bn5_g = F(39), *bn5_b = F(40), *bn5_m = F(41), *bn5_v = F(42);
    const float* bn7_g = F(43), *bn7_b = F(44), *bn7_m = F(45), *bn7_v = F(46);
    const float* bn9_g = F(47), *bn9_b = F(48), *bn9_m = F(49), *bn9_v = F(50);
    const float* bnl1_g = F(51), *bnl1_b = F(52), *bnl1_m = F(53), *bnl1_v = F(54);
    const float* bnl2_g = F(55), *bnl2_b = F(56), *bnl2_m = F(57), *bnl2_v = F(58);
    const float* bnd1_g = F(59), *bnd1_b = F(60), *bnd1_m = F(61), *bnd1_v = F(62);
    const float* bnd2_g = F(63), *bnd2_b = F(64), *bnd2_m = F(65), *bnd2_v = F(66);
    #undef F

    float* ws = (float*)d_ws;
    float* concat = ws;                         // 512*128*192 = 12,582,912 floats
    float* fused  = concat + 12582912;          // 512*128*128 =  8,388,608
    float* l1out  = fused + 8388608;            // 512*128*256 = 16,777,216
    float* l2out  = concat;                     // reuse concat region (needs 8,388,608)
    float* msum   = fused;                      // reuse fused region (needs 131,072)
    float* outp   = (float*)d_out;

    // conv blocks (register-tiled)
    conv_block_v2<5><<<dim3(512,4), dim3(256), 0, stream>>>(
        x, conv5_w, conv5_b, bn5_g, bn5_b, bn5_m, bn5_v, concat, 0);
    conv_block_v2<7><<<dim3(512,4), dim3(256), 0, stream>>>(
        x, conv7_w, conv7_b, bn7_g, bn7_b, bn7_m, bn7_v, concat, 64);
    conv_block_v2<9><<<dim3(512,4), dim3(256), 0, stream>>>(
        x, conv9_w, conv9_b, bn9_g, bn9_b, bn9_m, bn9_v, concat, 128);

    // 1x1 fuse
    fuse_v2<<<dim3(4096), dim3(256), 0, stream>>>(concat, fuse_w, fuse_b, fused);

    // SE (in place)
    se_kernel<<<dim3(512), dim3(128), 0, stream>>>(fused, se_w1, se_b1, se_w2, se_b2);

    // BiLSTM 1 (+bn_l1)
    lstm1_kernel<<<dim3(128,2), dim3(1024), 0, stream>>>(
        fused, l1f_k, l1f_r, l1f_b, l1b_k, l1b_r, l1b_b,
        bnl1_g, bnl1_b, bnl1_m, bnl1_v, l1out);

    // BiLSTM 2 (+bn_l2)
    lstm2_kernel<<<dim3(128,2), dim3(512), 0, stream>>>(
        l1out, l2f_k, l2f_r, l2f_b, l2b_k, l2b_r, l2b_b,
        bnl2_g, bnl2_b, bnl2_m, bnl2_v, l2out);

    // MHSA -> per-channel T-mean
    mhsa_kernel<<<dim3(512,8), dim3(128), 0, stream>>>(
        l2out, wq, bq, wk, bk, wv, bv, msum);

    // wo + dense head
    head_kernel<<<dim3(512), dim3(256), 0, stream>>>(
        msum, wo, bo,
        d1_w, d1_b, bnd1_g, bnd1_b, bnd1_m, bnd1_v,
        d2_w, d2_b, bnd2_g, bnd2_b, bnd2_m, bnd2_v,
        d3_w, d3_b, outp);

    (void)in_sizes; (void)n_in; (void)out_size; (void)ws_size;
}

// Round 3
// 1667.769 us; speedup vs baseline: 4.3863x; 2.3160x over previous
//
#include <hip/hip_runtime.h>

#define EPS 1e-3f

typedef __attribute__((ext_vector_type(8))) short bf16x8;
typedef __attribute__((ext_vector_type(4))) float f32x4;

__device__ __forceinline__ float sigm(float x){ return 1.0f/(1.0f + __expf(-x)); }
__device__ __forceinline__ float tanhfast(float x){ return 1.0f - 2.0f/(1.0f + __expf(2.0f*x)); }

__device__ __forceinline__ unsigned short f2b(float f){
    union { float f; unsigned u; } v; v.f = f;
    unsigned r = v.u + 0x7FFFu + ((v.u >> 16) & 1u);
    return (unsigned short)(r >> 16);
}
__device__ __forceinline__ float b2f(unsigned short h){
    union { unsigned u; float f; } v; v.u = ((unsigned)h) << 16; return v.f;
}

// ---------------- conv(K) + bias + relu + BN + maxpool2 -> concat slice (register-tiled) ----------------
template<int K>
__global__ void __launch_bounds__(256)
conv_block_v2(const float* __restrict__ x,   // [512,256,78]
              const float* __restrict__ w,   // [K,78,64]
              const float* __restrict__ bias,
              const float* __restrict__ bng,
              const float* __restrict__ bnb,
              const float* __restrict__ bnm,
              const float* __restrict__ bnv,
              float* __restrict__ out,       // [512,128,192]
              int cbase)
{
    constexpr int PAD = K / 2;
    constexpr int OFF = 4 - PAD;
    constexpr int NX  = 3 + K;

    __shared__ float xt[78][73];

    const int b    = blockIdx.x;
    const int tile = blockIdx.y;
    const int tid  = threadIdx.x;
    const int tbase = tile*64 - 4;

    for (int idx = tid; idx < 72*78; idx += 256){
        int u  = idx / 78;
        int ci = idx - u*78;
        int t  = tbase + u;
        xt[ci][u] = (t >= 0 && t < 256) ? x[((size_t)b*256 + t)*78 + ci] : 0.f;
    }
    __syncthreads();

    const int cog = tid & 15;
    const int tg  = tid >> 4;
    const int co  = cog * 4;

    float acc[4][4];
    {
        const float4 b4 = *(const float4*)(bias + co);
        #pragma unroll
        for (int r = 0; r < 4; ++r){
            acc[r][0] = b4.x; acc[r][1] = b4.y; acc[r][2] = b4.z; acc[r][3] = b4.w;
        }
    }

    for (int ci = 0; ci < 78; ++ci){
        float xv[NX];
        #pragma unroll
        for (int q = 0; q < NX; ++q) xv[q] = xt[ci][tg*4 + OFF + q];
        #pragma unroll
        for (int k = 0; k < K; ++k){
            const float4 wv = *(const float4*)(w + ((size_t)(k*78 + ci))*64 + co);
            #pragma unroll
            for (int r = 0; r < 4; ++r){
                acc[r][0] = fmaf(xv[r+k], wv.x, acc[r][0]);
                acc[r][1] = fmaf(xv[r+k], wv.y, acc[r][1]);
                acc[r][2] = fmaf(xv[r+k], wv.z, acc[r][2]);
                acc[r][3] = fmaf(xv[r+k], wv.w, acc[r][3]);
            }
        }
    }

    float s[4], sh[4];
    #pragma unroll
    for (int c = 0; c < 4; ++c){
        s[c]  = bng[co+c] * rsqrtf(bnv[co+c] + EPS);
        sh[c] = bnb[co+c] - bnm[co+c] * s[c];
    }
    #pragma unroll
    for (int pr = 0; pr < 2; ++pr){
        float4 o;
        float v0, v1;
        v0 = fmaxf(acc[2*pr][0],0.f)*s[0]+sh[0]; v1 = fmaxf(acc[2*pr+1][0],0.f)*s[0]+sh[0]; o.x = fmaxf(v0,v1);
        v0 = fmaxf(acc[2*pr][1],0.f)*s[1]+sh[1]; v1 = fmaxf(acc[2*pr+1][1],0.f)*s[1]+sh[1]; o.y = fmaxf(v0,v1);
        v0 = fmaxf(acc[2*pr][2],0.f)*s[2]+sh[2]; v1 = fmaxf(acc[2*pr+1][2],0.f)*s[2]+sh[2]; o.z = fmaxf(v0,v1);
        v0 = fmaxf(acc[2*pr][3],0.f)*s[3]+sh[3]; v1 = fmaxf(acc[2*pr+1][3],0.f)*s[3]+sh[3]; o.w = fmaxf(v0,v1);
        int t_out = tile*32 + tg*2 + pr;
        *(float4*)(out + ((size_t)b*128 + t_out)*192 + cbase + co) = o;
    }
}

// ---------------- 1x1 fuse conv ----------------
__global__ void __launch_bounds__(256)
fuse_v2(const float* __restrict__ in,
        const float* __restrict__ w,
        const float* __restrict__ bias,
        float* __restrict__ out)
{
    __shared__ float xl[16][192];
    const int tid = threadIdx.x;
    const size_t row0 = (size_t)blockIdx.x * 16;

    {
        const float4* ip = (const float4*)(in + row0*192);
        float4* xp = (float4*)&xl[0][0];
        #pragma unroll
        for (int idx = tid; idx < 768; idx += 256) xp[idx] = ip[idx];
    }
    __syncthreads();

    const int co = tid & 127;
    const int rg = tid >> 7;
    float acc[8];
    {
        float bv = bias[co];
        #pragma unroll
        for (int r = 0; r < 8; ++r) acc[r] = bv;
    }

    for (int ci4 = 0; ci4 < 192; ci4 += 4){
        float wv0 = w[(ci4+0)*128 + co];
        float wv1 = w[(ci4+1)*128 + co];
        float wv2 = w[(ci4+2)*128 + co];
        float wv3 = w[(ci4+3)*128 + co];
        #pragma unroll
        for (int r = 0; r < 8; ++r){
            const float4 xr = *(const float4*)&xl[rg*8 + r][ci4];
            acc[r] = fmaf(xr.x, wv0, acc[r]);
            acc[r] = fmaf(xr.y, wv1, acc[r]);
            acc[r] = fmaf(xr.z, wv2, acc[r]);
            acc[r] = fmaf(xr.w, wv3, acc[r]);
        }
    }
    #pragma unroll
    for (int r = 0; r < 8; ++r)
        out[(row0 + rg*8 + r)*128 + co] = acc[r];
}

// ---------------- SE ----------------
__global__ void se_kernel(float* __restrict__ fused,
                          const float* __restrict__ w1, const float* __restrict__ b1,
                          const float* __restrict__ w2, const float* __restrict__ b2)
{
    int b = blockIdx.x, c = threadIdx.x;
    __shared__ float sv[128];
    __shared__ float rv[8];
    float* fp = fused + (size_t)b*128*128 + c;
    float acc = 0.f;
    for (int t = 0; t < 128; ++t) acc += fp[t*128];
    sv[c] = acc * (1.f/128.f);
    __syncthreads();
    if (c < 8){
        float r = b1[c];
        for (int i = 0; i < 128; ++i) r = fmaf(sv[i], w1[i*8 + c], r);
        rv[c] = fmaxf(r, 0.f);
    }
    __syncthreads();
    float e = b2[c];
    #pragma unroll
    for (int j = 0; j < 8; ++j) e = fmaf(rv[j], w2[j*128 + c], e);
    e = sigm(e);
    for (int t = 0; t < 128; ++t) fp[t*128] *= e;
}

// ---------------- xp GEMM: out[M,N](bf16) = A[M,K] @ W[K,N] + bias ----------------
// BM=128, BN=128, BK=32; 256 threads = 4 waves (2x2), wave tile 64x64.
// Fragment convention (mfma_f32_16x16x32_bf16, m89-verified):
//  A-frag: lane l holds A[m=l&15][k=(l>>4)*8+e]; B-frag: B[k=(l>>4)*8+e][n=l&15]
//  D: lane l reg r -> D[m=(l>>4)*4+r][n=l&15]
template<int K, bool ABF16>
__global__ void __launch_bounds__(256)
xp_gemm(const void* __restrict__ Av, const float* __restrict__ W,
        const float* __restrict__ bias, unsigned short* __restrict__ outp, int N)
{
    __shared__ unsigned short Asm[128][40];      // [m][k] +8 pad
    __shared__ unsigned short Bsm[8][64][8];     // [nt][fraglane][e]

    const int tid  = threadIdx.x;
    const int lane = tid & 63;
    const int wv   = tid >> 6;
    const int wm   = wv & 1;
    const int wn   = wv >> 1;
    const size_t m0 = (size_t)blockIdx.x * 128;
    const int n0   = blockIdx.y * 128;

    f32x4 acc[4][4];
    #pragma unroll
    for (int nt = 0; nt < 4; ++nt){
        float bv = bias[n0 + wn*64 + nt*16 + (lane & 15)];
        #pragma unroll
        for (int mt = 0; mt < 4; ++mt)
            acc[mt][nt] = (f32x4){bv, bv, bv, bv};
    }

    const int bn = tid & 127;
    const int bg = tid >> 7;

    for (int k0 = 0; k0 < K; k0 += 32){
        __syncthreads();
        if constexpr (!ABF16){
            const float* Ag = (const float*)Av;
            #pragma unroll
            for (int i = 0; i < 2; ++i){
                int g = tid + i*256;
                int r = g >> 2, c8 = g & 3;
                float4 d0 = *(const float4*)(Ag + (m0 + r)*K + k0 + c8*8);
                float4 d1 = *(const float4*)(Ag + (m0 + r)*K + k0 + c8*8 + 4);
                union { unsigned short s[8]; uint4 v; } u;
                u.s[0]=f2b(d0.x); u.s[1]=f2b(d0.y); u.s[2]=f2b(d0.z); u.s[3]=f2b(d0.w);
                u.s[4]=f2b(d1.x); u.s[5]=f2b(d1.y); u.s[6]=f2b(d1.z); u.s[7]=f2b(d1.w);
                *(uint4*)&Asm[r][c8*8] = u.v;
            }
        } else {
            const unsigned short* Ag = (const unsigned short*)Av;
            #pragma unroll
            for (int i = 0; i < 2; ++i){
                int g = tid + i*256;
                int r = g >> 2, c8 = g & 3;
                uint4 d = *(const uint4*)(Ag + (m0 + r)*K + k0 + c8*8);
                *(uint4*)&Asm[r][c8*8] = d;
            }
        }
        {
            union { unsigned short s[8]; uint4 v; } u0, u1;
            #pragma unroll
            for (int q = 0; q < 8; ++q){
                u0.s[q] = f2b(W[(size_t)(k0 + bg*16 + q)*N + n0 + bn]);
                u1.s[q] = f2b(W[(size_t)(k0 + bg*16 + 8 + q)*N + n0 + bn]);
            }
            int nt = bn >> 4, lo = bn & 15;
            *(uint4*)&Bsm[nt][lo + 16*(2*bg)][0]   = u0.v;
            *(uint4*)&Bsm[nt][lo + 16*(2*bg+1)][0] = u1.v;
        }
        __syncthreads();

        bf16x8 af[4], bfr[4];
        #pragma unroll
        for (int mt = 0; mt < 4; ++mt)
            af[mt] = *(const bf16x8*)&Asm[wm*64 + mt*16 + (lane & 15)][(lane >> 4)*8];
        #pragma unroll
        for (int nt = 0; nt < 4; ++nt)
            bfr[nt] = *(const bf16x8*)&Bsm[wn*4 + nt][lane][0];
        #pragma unroll
        for (int mt = 0; mt < 4; ++mt)
            #pragma unroll
            for (int nt = 0; nt < 4; ++nt)
                acc[mt][nt] = __builtin_amdgcn_mfma_f32_16x16x32_bf16(af[mt], bfr[nt], acc[mt][nt], 0, 0, 0);
    }

    #pragma unroll
    for (int mt = 0; mt < 4; ++mt)
        #pragma unroll
        for (int nt = 0; nt < 4; ++nt)
            #pragma unroll
            for (int r = 0; r < 4; ++r){
                size_t row = m0 + wm*64 + mt*16 + (lane >> 4)*4 + r;
                int    col = n0 + wn*64 + nt*16 + (lane & 15);
                outp[row*N + col] = f2b(acc[mt][nt][r]);
            }
}

// ---------------- LSTM recurrence: z_t = xp_t + h_{t-1} @ R; R in VGPR frags ----------------
// Block: 4 batch rows (padded to M=16), 512 threads = 8 waves; wave w owns z cols [w*Z/8, (w+1)*Z/8)
template<int U, bool OUT_BF16>
__global__ void __launch_bounds__(512)
lstm_rec(const unsigned short* __restrict__ xpf, const unsigned short* __restrict__ xpb,
         const float* __restrict__ Rf, const float* __restrict__ Rb,
         const float* __restrict__ bng, const float* __restrict__ bnb,
         const float* __restrict__ bnm, const float* __restrict__ bnv,
         void* __restrict__ outv, int dir_param)
{
    constexpr int Z   = 4*U;
    constexpr int KT  = U/32;       // k-tiles
    constexpr int NTW = Z/128;      // n-tiles per wave
    constexpr int HP  = U + 8;

    __shared__ unsigned short h_lds[16][HP];
    __shared__ float z_lds[4][Z];

    const int tid  = threadIdx.x;
    const int lane = tid & 63;
    const int wv   = tid >> 6;
    const int dir  = (gridDim.y == 2) ? (int)blockIdx.y : dir_param;
    const int b0   = blockIdx.x * 4;
    const int ncol0 = wv * (Z/8);

    const unsigned short* xp = dir ? xpb : xpf;
    const float* Rg = dir ? Rb : Rf;

    for (int i = tid; i < 16*HP; i += 512) ((unsigned short*)h_lds)[i] = 0;

    bf16x8 rf[KT][NTW];
    {
        const int kb = (lane >> 4) * 8;
        const int nc = lane & 15;
        #pragma unroll
        for (int kt = 0; kt < KT; ++kt)
            #pragma unroll
            for (int nt = 0; nt < NTW; ++nt){
                union { unsigned short s[8]; bf16x8 v; } u;
                #pragma unroll
                for (int e = 0; e < 8; ++e)
                    u.s[e] = f2b(Rg[(size_t)(kt*32 + kb + e)*Z + ncol0 + nt*16 + nc]);
                rf[kt][nt] = u.v;
            }
    }

    const int u_  = tid % U;
    const int r_  = tid / U;
    const bool gate = (tid < 4*U);
    float c_ = 0.f;
    float bns = 0.f, bnsh = 0.f;
    const int ch = dir*U + u_;
    if (gate){
        bns  = bng[ch] * rsqrtf(bnv[ch] + EPS);
        bnsh = bnb[ch] - bnm[ch]*bns;
    }
    __syncthreads();

    for (int ts = 0; ts < 128; ++ts){
        const int t = dir ? 127 - ts : ts;
        unsigned short xq0=0,xq1=0,xq2=0,xq3=0;
        if (gate){
            const unsigned short* xr = xp + ((size_t)(b0 + r_)*128 + t)*Z + u_;
            xq0 = xr[0]; xq1 = xr[U]; xq2 = xr[2*U]; xq3 = xr[3*U];
        }
        bf16x8 af[KT];
        #pragma unroll
        for (int kt = 0; kt < KT; ++kt)
            af[kt] = *(const bf16x8*)&h_lds[lane & 15][kt*32 + (lane >> 4)*8];
        f32x4 acc[NTW];
        #pragma unroll
        for (int nt = 0; nt < NTW; ++nt) acc[nt] = (f32x4){0.f,0.f,0.f,0.f};
        #pragma unroll
        for (int kt = 0; kt < KT; ++kt)
            #pragma unroll
            for (int nt = 0; nt < NTW; ++nt)
                acc[nt] = __builtin_amdgcn_mfma_f32_16x16x32_bf16(af[kt], rf[kt][nt], acc[nt], 0, 0, 0);
        if ((lane >> 4) == 0){
            #pragma unroll
            for (int nt = 0; nt < NTW; ++nt)
                #pragma unroll
                for (int r = 0; r < 4; ++r)
                    z_lds[r][ncol0 + nt*16 + (lane & 15)] = acc[nt][r];
        }
        __syncthreads();
        if (gate){
            float z0 = z_lds[r_][u_      ] + b2f(xq0);
            float z1 = z_lds[r_][u_ +  U ] + b2f(xq1);
            float z2 = z_lds[r_][u_ + 2*U] + b2f(xq2);
            float z3 = z_lds[r_][u_ + 3*U] + b2f(xq3);
            float iv = sigm(z0), fv = sigm(z1), gv = tanhfast(z2), ov = sigm(z3);
            c_ = fv*c_ + iv*gv;
            float h = ov * tanhfast(c_);
            h_lds[r_][u_] = f2b(h);
            float hb = fmaf(h, bns, bnsh);
            size_t oidx = ((size_t)(b0 + r_)*128 + t)*(size_t)(2*U) + ch;
            if constexpr (OUT_BF16) ((unsigned short*)outv)[oidx] = f2b(hb);
            else                    ((float*)outv)[oidx] = hb;
        }
        __syncthreads();
    }
}

// ---------------- MHSA per (b, head) ----------------
__global__ void __launch_bounds__(128)
mhsa_kernel(const float* __restrict__ h2,
            const float* __restrict__ wq, const float* __restrict__ bq,
            const float* __restrict__ wk, const float* __restrict__ bk,
            const float* __restrict__ wv, const float* __restrict__ bv,
            float* __restrict__ msum)
{
    int b = blockIdx.x, hd = blockIdx.y, t = threadIdx.x;
    int cb = hd * 32;
    __shared__ float kx[128][33];
    __shared__ float vx[128][33];
    __shared__ float red[128][33];

    float q[32], kk[32], vv[32];
    #pragma unroll
    for (int d = 0; d < 32; ++d){ q[d] = bq[cb+d]; kk[d] = bk[cb+d]; vv[d] = bv[cb+d]; }
    const float* xr = h2 + ((size_t)b*128 + t)*128;
    for (int i = 0; i < 128; ++i){
        float xv = xr[i];
        const float* wqp = wq + i*256 + cb;
        const float* wkp = wk + i*256 + cb;
        const float* wvp = wv + i*256 + cb;
        #pragma unroll
        for (int d = 0; d < 32; ++d){
            q[d]  = fmaf(xv, wqp[d], q[d]);
            kk[d] = fmaf(xv, wkp[d], kk[d]);
            vv[d] = fmaf(xv, wvp[d], vv[d]);
        }
    }
    #pragma unroll
    for (int d = 0; d < 32; ++d){ kx[t][d] = kk[d]; vx[t][d] = vv[d]; }
    __syncthreads();

    float m = -1e30f, l = 0.f, acc[32];
    #pragma unroll
    for (int d = 0; d < 32; ++d) acc[d] = 0.f;
    const float scale = 0.17677669529663687f;
    for (int tp = 0; tp < 128; ++tp){
        float s = 0.f;
        #pragma unroll
        for (int d = 0; d < 32; ++d) s = fmaf(q[d], kx[tp][d], s);
        s *= scale;
        float mn = fmaxf(m, s);
        float corr = __expf(m - mn);
        float p = __expf(s - mn);
        l = l * corr + p;
        #pragma unroll
        for (int d = 0; d < 32; ++d) acc[d] = fmaf(p, vx[tp][d], acc[d]*corr);
        m = mn;
    }
    float inv = 1.f / l;
    #pragma unroll
    for (int d = 0; d < 32; ++d) red[t][d] = acc[d] * inv;
    __syncthreads();
    if (t < 32){
        float s = 0.f;
        for (int i = 0; i < 128; ++i) s += red[i][t];
        msum[(size_t)b*256 + cb + t] = s * (1.f/128.f);
    }
}

// ---------------- head ----------------
__global__ void __launch_bounds__(256)
head_kernel(const float* __restrict__ msum,
            const float* __restrict__ wo, const float* __restrict__ bo,
            const float* __restrict__ d1w, const float* __restrict__ d1b,
            const float* __restrict__ g1, const float* __restrict__ b1,
            const float* __restrict__ m1, const float* __restrict__ v1,
            const float* __restrict__ d2w, const float* __restrict__ d2b,
            const float* __restrict__ g2, const float* __restrict__ b2,
            const float* __restrict__ m2, const float* __restrict__ v2,
            const float* __restrict__ d3w, const float* __restrict__ d3b,
            float* __restrict__ outp)
{
    int b = blockIdx.x, j = threadIdx.x;
    __shared__ float s1[256];
    __shared__ float s2[256];
    const float* mr = msum + (size_t)b*256;
    float acc = bo[j];
    #pragma unroll 4
    for (int i = 0; i < 256; ++i) acc = fmaf(mr[i], wo[i*256 + j], acc);
    s1[j] = acc;
    __syncthreads();
    float a1 = d1b[j];
    #pragma unroll 4
    for (int i = 0; i < 256; ++i) a1 = fmaf(s1[i], d1w[i*256 + j], a1);
    a1 = fmaxf(a1, 0.f);
    float sc1 = g1[j] * rsqrtf(v1[j] + EPS);
    a1 = a1 * sc1 + (b1[j] - m1[j] * sc1);
    s2[j] = a1;
    __syncthreads();
    if (j < 128){
        float a2 = d2b[j];
        #pragma unroll 4
        for (int i = 0; i < 256; ++i) a2 = fmaf(s2[i], d2w[i*128 + j], a2);
        a2 = fmaxf(a2, 0.f);
        float sc2 = g2[j] * rsqrtf(v2[j] + EPS);
        a2 = a2 * sc2 + (b2[j] - m2[j] * sc2);
        s1[j] = a2;
    }
    __syncthreads();
    if (j == 0){
        float a3 = d3b[0];
        for (int i = 0; i < 128; ++i) a3 = fmaf(s1[i], d3w[i], a3);
        outp[b] = sigm(a3);
    }
}

extern "C" void kernel_launch(void* const* d_in, const int* in_sizes, int n_in,
                              void* d_out, int out_size, void* d_ws, size_t ws_size,
                              hipStream_t stream)
{
    #define F(i) ((const float*)d_in[i])
    const float* x       = F(0);
    const float* conv5_w = F(1);
    const float* conv7_w = F(2);
    const float* conv9_w = F(3);
    const float* fuse_w  = F(4);
    const float* se_w1   = F(5);
    const float* se_w2   = F(6);
    const float* l1f_k   = F(7);
    const float* l1f_r   = F(8);
    const float* l1b_k   = F(9);
    const float* l1b_r   = F(10);
    const float* l2f_k   = F(11);
    const float* l2f_r   = F(12);
    const float* l2b_k   = F(13);
    const float* l2b_r   = F(14);
    const float* wq      = F(15);
    const float* wk      = F(16);
    const float* wv      = F(17);
    const float* wo      = F(18);
    const float* d1_w    = F(19);
    const float* d2_w    = F(20);
    const float* d3_w    = F(21);
    const float* conv5_b = F(22);
    const float* conv7_b = F(23);
    const float* conv9_b = F(24);
    const float* fuse_b  = F(25);
    const float* se_b1   = F(26);
    const float* se_b2   = F(27);
    const float* l1f_b   = F(28);
    const float* l1b_b   = F(29);
    const float* l2f_b   = F(30);
    const float* l2b_b   = F(31);
    const float* bq      = F(32);
    const float* bk      = F(33);
    const float* bv      = F(34);
    const float* bo      = F(35);
    const float* d1_b    = F(36);
    const float* d2_b    = F(37);
    const float* d3_b    = F(38);
    const float* bn5_g = F(39), *bn5_b = F(40), *bn5_m = F(41), *bn5_v = F(42);
    const float* bn7_g = F(43), *bn7_b = F(44), *bn7_m = F(45), *bn7_v = F(46);
    const float* bn9_g = F(47), *bn9_b = F(48), *bn9_m = F(49), *bn9_v = F(50);
    const float* bnl1_g = F(51), *bnl1_b = F(52), *bnl1_m = F(53), *bnl1_v = F(54);
    const float* bnl2_g = F(55), *bnl2_b = F(56), *bnl2_m = F(57), *bnl2_v = F(58);
    const float* bnd1_g = F(59), *bnd1_b = F(60), *bnd1_m = F(61), *bnd1_v = F(62);
    const float* bnd2_g = F(63), *bnd2_b = F(64), *bnd2_m = F(65), *bnd2_v = F(66);
    #undef F

    float* ws = (float*)d_ws;
    // float-offset layout:
    // fused  [0, 8388608)         fp32 [65536,128]
    // concat [8388608, 20971520)  fp32 [65536,192]  -> later reused as l1out bf16 (8.39M slots)
    // xp1f   [20971520, ...)      bf16 [65536,512]  (16777216 float slots)
    // xp1b   [37748736, ...)      bf16 (BIG path only)
    // xp2f   [0, ...)             bf16 [65536,256] (8388608 slots, fused region reuse)
    // xp2b   [20971520, ...)      bf16 (xp1 region reuse)
    // l2out  [29360128, 37748736) fp32 [65536,128]
    // msum   [0, 131072)          (xp2f region reuse, after lstm2)
    float* fused  = ws;
    float* concat = ws + 8388608;
    unsigned short* xp1f = (unsigned short*)(ws + 20971520);
    unsigned short* xp1b = (unsigned short*)(ws + 37748736);
    unsigned short* l1out = (unsigned short*)(ws + 8388608);
    unsigned short* xp2f = (unsigned short*)(ws + 0);
    unsigned short* xp2b = (unsigned short*)(ws + 20971520);
    float* l2out  = ws + 29360128;
    float* msum   = ws + 0;
    float* outp   = (float*)d_out;

    const bool big = (ws_size >= 218103808ULL);   // 54,525,952 floats

    conv_block_v2<5><<<dim3(512,4), dim3(256), 0, stream>>>(
        x, conv5_w, conv5_b, bn5_g, bn5_b, bn5_m, bn5_v, concat, 0);
    conv_block_v2<7><<<dim3(512,4), dim3(256), 0, stream>>>(
        x, conv7_w, conv7_b, bn7_g, bn7_b, bn7_m, bn7_v, concat, 64);
    conv_block_v2<9><<<dim3(512,4), dim3(256), 0, stream>>>(
        x, conv9_w, conv9_b, bn9_g, bn9_b, bn9_m, bn9_v, concat, 128);

    fuse_v2<<<dim3(4096), dim3(256), 0, stream>>>(concat, fuse_w, fuse_b, fused);
    se_kernel<<<dim3(512), dim3(128), 0, stream>>>(fused, se_w1, se_b1, se_w2, se_b2);

    if (big){
        xp_gemm<128,false><<<dim3(512,4), dim3(256), 0, stream>>>(fused, l1f_k, l1f_b, xp1f, 512);
        xp_gemm<128,false><<<dim3(512,4), dim3(256), 0, stream>>>(fused, l1b_k, l1b_b, xp1b, 512);
        lstm_rec<128,true><<<dim3(128,2), dim3(512), 0, stream>>>(
            xp1f, xp1b, l1f_r, l1b_r, bnl1_g, bnl1_b, bnl1_m, bnl1_v, l1out, 0);
    } else {
        xp_gemm<128,false><<<dim3(512,4), dim3(256), 0, stream>>>(fused, l1f_k, l1f_b, xp1f, 512);
        lstm_rec<128,true><<<dim3(128,1), dim3(512), 0, stream>>>(
            xp1f, xp1f, l1f_r, l1b_r, bnl1_g, bnl1_b, bnl1_m, bnl1_v, l1out, 0);
        xp_gemm<128,false><<<dim3(512,4), dim3(256), 0, stream>>>(fused, l1b_k, l1b_b, xp1f, 512);
        lstm_rec<128,true><<<dim3(128,1), dim3(512), 0, stream>>>(
            xp1f, xp1f, l1f_r, l1b_r, bnl1_g, bnl1_b, bnl1_m, bnl1_v, l1out, 1);
    }

    xp_gemm<256,true><<<dim3(512,2), dim3(256), 0, stream>>>(l1out, l2f_k, l2f_b, xp2f, 256);
    xp_gemm<256,true><<<dim3(512,2), dim3(256), 0, stream>>>(l1out, l2b_k, l2b_b, xp2b, 256);
    lstm_rec<64,false><<<dim3(128,2), dim3(512), 0, stream>>>(
        xp2f, xp2b, l2f_r, l2b_r, bnl2_g, bnl2_b, bnl2_m, bnl2_v, l2out, 0);

    mhsa_kernel<<<dim3(512,8), dim3(128), 0, stream>>>(
        l2out, wq, bq, wk, bk, wv, bv, msum);

    head_kernel<<<dim3(512), dim3(256), 0, stream>>>(
        msum, wo, bo,
        d1_w, d1_b, bnd1_g, bnd1_b, bnd1_m, bnd1_v,
        d2_w, d2_b, bnd2_g, bnd2_b, bnd2_m, bnd2_v,
        d3_w, d3_b, outp);

    (void)in_sizes; (void)n_in; (void)out_size;
}

// Round 4
// 1026.721 us; speedup vs baseline: 7.1250x; 1.6244x over previous
//
#include <hip/hip_runtime.h>

#define EPS 1e-3f

typedef __attribute__((ext_vector_type(8))) short bf16x8;
typedef __attribute__((ext_vector_type(4))) float f32x4;

__device__ __forceinline__ float sigm(float x){ return 1.0f/(1.0f + __expf(-x)); }
__device__ __forceinline__ float tanhfast(float x){ return 1.0f - 2.0f/(1.0f + __expf(2.0f*x)); }

__device__ __forceinline__ unsigned short f2b(float f){
    union { float f; unsigned u; } v; v.f = f;
    unsigned r = v.u + 0x7FFFu + ((v.u >> 16) & 1u);
    return (unsigned short)(r >> 16);
}
__device__ __forceinline__ float b2f(unsigned short h){
    union { unsigned u; float f; } v; v.u = ((unsigned)h) << 16; return v.f;
}

// ---------------- conv(K) + bias + relu + BN + maxpool2 -> concat slice (register-tiled) ----------------
template<int K>
__global__ void __launch_bounds__(256)
conv_block_v2(const float* __restrict__ x,   // [512,256,78]
              const float* __restrict__ w,   // [K,78,64]
              const float* __restrict__ bias,
              const float* __restrict__ bng,
              const float* __restrict__ bnb,
              const float* __restrict__ bnm,
              const float* __restrict__ bnv,
              float* __restrict__ out,       // [512,128,192]
              int cbase)
{
    constexpr int PAD = K / 2;
    constexpr int OFF = 4 - PAD;
    constexpr int NX  = 3 + K;

    __shared__ float xt[78][73];

    const int b    = blockIdx.x;
    const int tile = blockIdx.y;
    const int tid  = threadIdx.x;
    const int tbase = tile*64 - 4;

    for (int idx = tid; idx < 72*78; idx += 256){
        int u  = idx / 78;
        int ci = idx - u*78;
        int t  = tbase + u;
        xt[ci][u] = (t >= 0 && t < 256) ? x[((size_t)b*256 + t)*78 + ci] : 0.f;
    }
    __syncthreads();

    const int cog = tid & 15;
    const int tg  = tid >> 4;
    const int co  = cog * 4;

    float acc[4][4];
    {
        const float4 b4 = *(const float4*)(bias + co);
        #pragma unroll
        for (int r = 0; r < 4; ++r){
            acc[r][0] = b4.x; acc[r][1] = b4.y; acc[r][2] = b4.z; acc[r][3] = b4.w;
        }
    }

    for (int ci = 0; ci < 78; ++ci){
        float xv[NX];
        #pragma unroll
        for (int q = 0; q < NX; ++q) xv[q] = xt[ci][tg*4 + OFF + q];
        #pragma unroll
        for (int k = 0; k < K; ++k){
            const float4 wv = *(const float4*)(w + ((size_t)(k*78 + ci))*64 + co);
            #pragma unroll
            for (int r = 0; r < 4; ++r){
                acc[r][0] = fmaf(xv[r+k], wv.x, acc[r][0]);
                acc[r][1] = fmaf(xv[r+k], wv.y, acc[r][1]);
                acc[r][2] = fmaf(xv[r+k], wv.z, acc[r][2]);
                acc[r][3] = fmaf(xv[r+k], wv.w, acc[r][3]);
            }
        }
    }

    float s[4], sh[4];
    #pragma unroll
    for (int c = 0; c < 4; ++c){
        s[c]  = bng[co+c] * rsqrtf(bnv[co+c] + EPS);
        sh[c] = bnb[co+c] - bnm[co+c] * s[c];
    }
    #pragma unroll
    for (int pr = 0; pr < 2; ++pr){
        float4 o;
        float v0, v1;
        v0 = fmaxf(acc[2*pr][0],0.f)*s[0]+sh[0]; v1 = fmaxf(acc[2*pr+1][0],0.f)*s[0]+sh[0]; o.x = fmaxf(v0,v1);
        v0 = fmaxf(acc[2*pr][1],0.f)*s[1]+sh[1]; v1 = fmaxf(acc[2*pr+1][1],0.f)*s[1]+sh[1]; o.y = fmaxf(v0,v1);
        v0 = fmaxf(acc[2*pr][2],0.f)*s[2]+sh[2]; v1 = fmaxf(acc[2*pr+1][2],0.f)*s[2]+sh[2]; o.z = fmaxf(v0,v1);
        v0 = fmaxf(acc[2*pr][3],0.f)*s[3]+sh[3]; v1 = fmaxf(acc[2*pr+1][3],0.f)*s[3]+sh[3]; o.w = fmaxf(v0,v1);
        int t_out = tile*32 + tg*2 + pr;
        *(float4*)(out + ((size_t)b*128 + t_out)*192 + cbase + co) = o;
    }
}

// ---------------- 1x1 fuse conv ----------------
__global__ void __launch_bounds__(256)
fuse_v2(const float* __restrict__ in,
        const float* __restrict__ w,
        const float* __restrict__ bias,
        float* __restrict__ out)
{
    __shared__ float xl[16][192];
    const int tid = threadIdx.x;
    const size_t row0 = (size_t)blockIdx.x * 16;

    {
        const float4* ip = (const float4*)(in + row0*192);
        float4* xp = (float4*)&xl[0][0];
        #pragma unroll
        for (int idx = tid; idx < 768; idx += 256) xp[idx] = ip[idx];
    }
    __syncthreads();

    const int co = tid & 127;
    const int rg = tid >> 7;
    float acc[8];
    {
        float bv = bias[co];
        #pragma unroll
        for (int r = 0; r < 8; ++r) acc[r] = bv;
    }

    for (int ci4 = 0; ci4 < 192; ci4 += 4){
        float wv0 = w[(ci4+0)*128 + co];
        float wv1 = w[(ci4+1)*128 + co];
        float wv2 = w[(ci4+2)*128 + co];
        float wv3 = w[(ci4+3)*128 + co];
        #pragma unroll
        for (int r = 0; r < 8; ++r){
            const float4 xr = *(const float4*)&xl[rg*8 + r][ci4];
            acc[r] = fmaf(xr.x, wv0, acc[r]);
            acc[r] = fmaf(xr.y, wv1, acc[r]);
            acc[r] = fmaf(xr.z, wv2, acc[r]);
            acc[r] = fmaf(xr.w, wv3, acc[r]);
        }
    }
    #pragma unroll
    for (int r = 0; r < 8; ++r)
        out[(row0 + rg*8 + r)*128 + co] = acc[r];
}

// ---------------- SE ----------------
__global__ void se_kernel(float* __restrict__ fused,
                          const float* __restrict__ w1, const float* __restrict__ b1,
                          const float* __restrict__ w2, const float* __restrict__ b2)
{
    int b = blockIdx.x, c = threadIdx.x;
    __shared__ float sv[128];
    __shared__ float rv[8];
    float* fp = fused + (size_t)b*128*128 + c;
    float acc = 0.f;
    for (int t = 0; t < 128; ++t) acc += fp[t*128];
    sv[c] = acc * (1.f/128.f);
    __syncthreads();
    if (c < 8){
        float r = b1[c];
        for (int i = 0; i < 128; ++i) r = fmaf(sv[i], w1[i*8 + c], r);
        rv[c] = fmaxf(r, 0.f);
    }
    __syncthreads();
    float e = b2[c];
    #pragma unroll
    for (int j = 0; j < 8; ++j) e = fmaf(rv[j], w2[j*128 + c], e);
    e = sigm(e);
    for (int t = 0; t < 128; ++t) fp[t*128] *= e;
}

// ---------------- xp GEMM: out[M,N] = A[M,K] @ W[K,N] + bias, bf16 out ----------------
// OUTMODE 0: standard [M,N]. OUTMODE 1: V-transposed per-head [b,head,d,t] (N=256, M=b*128+t).
template<int K, bool ABF16, int OUTMODE>
__global__ void __launch_bounds__(256)
xp_gemm(const void* __restrict__ Av, const float* __restrict__ W,
        const float* __restrict__ bias, unsigned short* __restrict__ outp, int N)
{
    __shared__ unsigned short Asm[128][40];
    __shared__ unsigned short Bsm[8][64][8];

    const int tid  = threadIdx.x;
    const int lane = tid & 63;
    const int wv   = tid >> 6;
    const int wm   = wv & 1;
    const int wn   = wv >> 1;
    const size_t m0 = (size_t)blockIdx.x * 128;
    const int n0   = blockIdx.y * 128;

    f32x4 acc[4][4];
    #pragma unroll
    for (int nt = 0; nt < 4; ++nt){
        float bv = bias[n0 + wn*64 + nt*16 + (lane & 15)];
        #pragma unroll
        for (int mt = 0; mt < 4; ++mt)
            acc[mt][nt] = (f32x4){bv, bv, bv, bv};
    }

    const int bn = tid & 127;
    const int bg = tid >> 7;

    for (int k0 = 0; k0 < K; k0 += 32){
        __syncthreads();
        if constexpr (!ABF16){
            const float* Ag = (const float*)Av;
            #pragma unroll
            for (int i = 0; i < 2; ++i){
                int g = tid + i*256;
                int r = g >> 2, c8 = g & 3;
                float4 d0 = *(const float4*)(Ag + (m0 + r)*K + k0 + c8*8);
                float4 d1 = *(const float4*)(Ag + (m0 + r)*K + k0 + c8*8 + 4);
                union { unsigned short s[8]; uint4 v; } u;
                u.s[0]=f2b(d0.x); u.s[1]=f2b(d0.y); u.s[2]=f2b(d0.z); u.s[3]=f2b(d0.w);
                u.s[4]=f2b(d1.x); u.s[5]=f2b(d1.y); u.s[6]=f2b(d1.z); u.s[7]=f2b(d1.w);
                *(uint4*)&Asm[r][c8*8] = u.v;
            }
        } else {
            const unsigned short* Ag = (const unsigned short*)Av;
            #pragma unroll
            for (int i = 0; i < 2; ++i){
                int g = tid + i*256;
                int r = g >> 2, c8 = g & 3;
                uint4 d = *(const uint4*)(Ag + (m0 + r)*K + k0 + c8*8);
                *(uint4*)&Asm[r][c8*8] = d;
            }
        }
        {
            union { unsigned short s[8]; uint4 v; } u0, u1;
            #pragma unroll
            for (int q = 0; q < 8; ++q){
                u0.s[q] = f2b(W[(size_t)(k0 + bg*16 + q)*N + n0 + bn]);
                u1.s[q] = f2b(W[(size_t)(k0 + bg*16 + 8 + q)*N + n0 + bn]);
            }
            int nt = bn >> 4, lo = bn & 15;
            *(uint4*)&Bsm[nt][lo + 16*(2*bg)][0]   = u0.v;
            *(uint4*)&Bsm[nt][lo + 16*(2*bg+1)][0] = u1.v;
        }
        __syncthreads();

        bf16x8 af[4], bfr[4];
        #pragma unroll
        for (int mt = 0; mt < 4; ++mt)
            af[mt] = *(const bf16x8*)&Asm[wm*64 + mt*16 + (lane & 15)][(lane >> 4)*8];
        #pragma unroll
        for (int nt = 0; nt < 4; ++nt)
            bfr[nt] = *(const bf16x8*)&Bsm[wn*4 + nt][lane][0];
        #pragma unroll
        for (int mt = 0; mt < 4; ++mt)
            #pragma unroll
            for (int nt = 0; nt < 4; ++nt)
                acc[mt][nt] = __builtin_amdgcn_mfma_f32_16x16x32_bf16(af[mt], bfr[nt], acc[mt][nt], 0, 0, 0);
    }

    #pragma unroll
    for (int mt = 0; mt < 4; ++mt)
        #pragma unroll
        for (int nt = 0; nt < 4; ++nt)
            #pragma unroll
            for (int r = 0; r < 4; ++r){
                size_t row = m0 + wm*64 + mt*16 + (lane >> 4)*4 + r;
                int    col = n0 + wn*64 + nt*16 + (lane & 15);
                if constexpr (OUTMODE == 0){
                    outp[row*N + col] = f2b(acc[mt][nt][r]);
                } else {
                    // vt[b][head][d][t]: b=row>>7, t=row&127, head=col>>5, d=col&31
                    size_t off = ((size_t)((row >> 7)*8 + (col >> 5))*32 + (col & 31))*128 + (row & 127);
                    outp[off] = f2b(acc[mt][nt][r]);
                }
            }
}

// ---------------- LSTM recurrence: z_t = xp_t + h_{t-1} @ R; R in VGPR frags ----------------
template<int U, bool OUT_BF16>
__global__ void __launch_bounds__(512)
lstm_rec(const unsigned short* __restrict__ xpf, const unsigned short* __restrict__ xpb,
         const float* __restrict__ Rf, const float* __restrict__ Rb,
         const float* __restrict__ bng, const float* __restrict__ bnb,
         const float* __restrict__ bnm, const float* __restrict__ bnv,
         void* __restrict__ outv, int dir_param)
{
    constexpr int Z   = 4*U;
    constexpr int KT  = U/32;
    constexpr int NTW = Z/128;
    constexpr int HP  = U + 8;

    __shared__ unsigned short h_lds[16][HP];
    __shared__ float z_lds[4][Z];

    const int tid  = threadIdx.x;
    const int lane = tid & 63;
    const int wv   = tid >> 6;
    const int dir  = (gridDim.y == 2) ? (int)blockIdx.y : dir_param;
    const int b0   = blockIdx.x * 4;
    const int ncol0 = wv * (Z/8);

    const unsigned short* xp = dir ? xpb : xpf;
    const float* Rg = dir ? Rb : Rf;

    for (int i = tid; i < 16*HP; i += 512) ((unsigned short*)h_lds)[i] = 0;

    bf16x8 rf[KT][NTW];
    {
        const int kb = (lane >> 4) * 8;
        const int nc = lane & 15;
        #pragma unroll
        for (int kt = 0; kt < KT; ++kt)
            #pragma unroll
            for (int nt = 0; nt < NTW; ++nt){
                union { unsigned short s[8]; bf16x8 v; } u;
                #pragma unroll
                for (int e = 0; e < 8; ++e)
                    u.s[e] = f2b(Rg[(size_t)(kt*32 + kb + e)*Z + ncol0 + nt*16 + nc]);
                rf[kt][nt] = u.v;
            }
    }

    const int u_  = tid % U;
    const int r_  = tid / U;
    const bool gate = (tid < 4*U);
    float c_ = 0.f;
    float bns = 0.f, bnsh = 0.f;
    const int ch = dir*U + u_;
    if (gate){
        bns  = bng[ch] * rsqrtf(bnv[ch] + EPS);
        bnsh = bnb[ch] - bnm[ch]*bns;
    }
    __syncthreads();

    for (int ts = 0; ts < 128; ++ts){
        const int t = dir ? 127 - ts : ts;
        unsigned short xq0=0,xq1=0,xq2=0,xq3=0;
        if (gate){
            const unsigned short* xr = xp + ((size_t)(b0 + r_)*128 + t)*Z + u_;
            xq0 = xr[0]; xq1 = xr[U]; xq2 = xr[2*U]; xq3 = xr[3*U];
        }
        bf16x8 af[KT];
        #pragma unroll
        for (int kt = 0; kt < KT; ++kt)
            af[kt] = *(const bf16x8*)&h_lds[lane & 15][kt*32 + (lane >> 4)*8];
        f32x4 acc[NTW];
        #pragma unroll
        for (int nt = 0; nt < NTW; ++nt) acc[nt] = (f32x4){0.f,0.f,0.f,0.f};
        #pragma unroll
        for (int kt = 0; kt < KT; ++kt)
            #pragma unroll
            for (int nt = 0; nt < NTW; ++nt)
                acc[nt] = __builtin_amdgcn_mfma_f32_16x16x32_bf16(af[kt], rf[kt][nt], acc[nt], 0, 0, 0);
        if ((lane >> 4) == 0){
            #pragma unroll
            for (int nt = 0; nt < NTW; ++nt)
                #pragma unroll
                for (int r = 0; r < 4; ++r)
                    z_lds[r][ncol0 + nt*16 + (lane & 15)] = acc[nt][r];
        }
        __syncthreads();
        if (gate){
            float z0 = z_lds[r_][u_      ] + b2f(xq0);
            float z1 = z_lds[r_][u_ +  U ] + b2f(xq1);
            float z2 = z_lds[r_][u_ + 2*U] + b2f(xq2);
            float z3 = z_lds[r_][u_ + 3*U] + b2f(xq3);
            float iv = sigm(z0), fv = sigm(z1), gv = tanhfast(z2), ov = sigm(z3);
            c_ = fv*c_ + iv*gv;
            float h = ov * tanhfast(c_);
            h_lds[r_][u_] = f2b(h);
            float hb = fmaf(h, bns, bnsh);
            size_t oidx = ((size_t)(b0 + r_)*128 + t)*(size_t)(2*U) + ch;
            if constexpr (OUT_BF16) ((unsigned short*)outv)[oidx] = f2b(hb);
            else                    ((float*)outv)[oidx] = hb;
        }
        __syncthreads();
    }
}

// ---------------- MFMA attention per (b, head): S=QK^T, softmax, PV, T-mean ----------------
__global__ void __launch_bounds__(256)
attn_kernel(const unsigned short* __restrict__ qb,   // [512*128, 256] (b,t) x (head*32+d)
            const unsigned short* __restrict__ kb,   // same layout
            const unsigned short* __restrict__ vb,   // [512,8,32,128] (b,head,d,t)
            float* __restrict__ msum)                // [512,256]
{
    __shared__ unsigned short p_lds[128][136];
    __shared__ float red[4][2][16];

    const int b  = blockIdx.x, hd = blockIdx.y;
    const int tid = threadIdx.x, lane = tid & 63, wv = tid >> 6;
    const int m0 = wv * 32;
    const int l15 = lane & 15, lg = lane >> 4;

    // Q fragments (A): lane holds Q[m0+mt*16+l15][lg*8+e]
    bf16x8 aq[2];
    #pragma unroll
    for (int mt = 0; mt < 2; ++mt)
        aq[mt] = *(const bf16x8*)(qb + ((size_t)(b*128 + m0 + mt*16 + l15))*256 + hd*32 + lg*8);

    // K fragments (B for S): B[d][kcol] = K[kcol][d]
    bf16x8 bk[8];
    #pragma unroll
    for (int nt = 0; nt < 8; ++nt)
        bk[nt] = *(const bf16x8*)(kb + ((size_t)(b*128 + nt*16 + l15))*256 + hd*32 + lg*8);

    f32x4 s[2][8];
    #pragma unroll
    for (int mt = 0; mt < 2; ++mt)
        #pragma unroll
        for (int nt = 0; nt < 8; ++nt) s[mt][nt] = (f32x4){0.f,0.f,0.f,0.f};
    #pragma unroll
    for (int mt = 0; mt < 2; ++mt)
        #pragma unroll
        for (int nt = 0; nt < 8; ++nt)
            s[mt][nt] = __builtin_amdgcn_mfma_f32_16x16x32_bf16(aq[mt], bk[nt], s[mt][nt], 0, 0, 0);

    const float scale = 0.17677669529663687f;   // 1/sqrt(32)
    #pragma unroll
    for (int mt = 0; mt < 2; ++mt)
        #pragma unroll
        for (int r = 0; r < 4; ++r){
            float mx = -1e30f;
            #pragma unroll
            for (int nt = 0; nt < 8; ++nt) mx = fmaxf(mx, s[mt][nt][r]);
            #pragma unroll
            for (int msk = 1; msk < 16; msk <<= 1) mx = fmaxf(mx, __shfl_xor(mx, msk, 64));
            float pv[8], sum = 0.f;
            #pragma unroll
            for (int nt = 0; nt < 8; ++nt){
                pv[nt] = __expf((s[mt][nt][r] - mx) * scale);
                sum += pv[nt];
            }
            #pragma unroll
            for (int msk = 1; msk < 16; msk <<= 1) sum += __shfl_xor(sum, msk, 64);
            float inv = 1.f / sum;
            int row = m0 + mt*16 + lg*4 + r;
            #pragma unroll
            for (int nt = 0; nt < 8; ++nt)
                p_lds[row][nt*16 + l15] = f2b(pv[nt] * inv);
        }
    __syncthreads();

    // PV: A=P[m][kcol], B[kcol][d] = V[kcol][d] = vt[d][kcol]
    f32x4 o[2][2];
    #pragma unroll
    for (int mt = 0; mt < 2; ++mt)
        #pragma unroll
        for (int dn = 0; dn < 2; ++dn) o[mt][dn] = (f32x4){0.f,0.f,0.f,0.f};
    bf16x8 bv[4][2];
    #pragma unroll
    for (int kt = 0; kt < 4; ++kt)
        #pragma unroll
        for (int dn = 0; dn < 2; ++dn)
            bv[kt][dn] = *(const bf16x8*)(vb + ((size_t)(b*8 + hd)*32 + dn*16 + l15)*128 + kt*32 + lg*8);
    #pragma unroll
    for (int mt = 0; mt < 2; ++mt)
        #pragma unroll
        for (int kt = 0; kt < 4; ++kt){
            bf16x8 ap = *(const bf16x8*)&p_lds[m0 + mt*16 + l15][kt*32 + lg*8];
            #pragma unroll
            for (int dn = 0; dn < 2; ++dn)
                o[mt][dn] = __builtin_amdgcn_mfma_f32_16x16x32_bf16(ap, bv[kt][dn], o[mt][dn], 0, 0, 0);
        }

    // T-mean over the 128 q-rows
    float sm[2];
    #pragma unroll
    for (int dn = 0; dn < 2; ++dn){
        float a = 0.f;
        #pragma unroll
        for (int mt = 0; mt < 2; ++mt)
            #pragma unroll
            for (int r = 0; r < 4; ++r) a += o[mt][dn][r];
        a += __shfl_xor(a, 16, 64);
        a += __shfl_xor(a, 32, 64);
        sm[dn] = a;
    }
    if (lg == 0){
        red[wv][0][l15] = sm[0];
        red[wv][1][l15] = sm[1];
    }
    __syncthreads();
    if (tid < 32){
        int dn = tid >> 4, n = tid & 15;
        float tot = red[0][dn][n] + red[1][dn][n] + red[2][dn][n] + red[3][dn][n];
        msum[(size_t)b*256 + hd*32 + dn*16 + n] = tot * (1.f/128.f);
    }
}

// ---------------- head ----------------
__global__ void __launch_bounds__(256)
head_kernel(const float* __restrict__ msum,
            const float* __restrict__ wo, const float* __restrict__ bo,
            const float* __restrict__ d1w, const float* __restrict__ d1b,
            const float* __restrict__ g1, const float* __restrict__ b1,
            const float* __restrict__ m1, const float* __restrict__ v1,
            const float* __restrict__ d2w, const float* __restrict__ d2b,
            const float* __restrict__ g2, const float* __restrict__ b2,
            const float* __restrict__ m2, const float* __restrict__ v2,
            const float* __restrict__ d3w, const float* __restrict__ d3b,
            float* __restrict__ outp)
{
    int b = blockIdx.x, j = threadIdx.x;
    __shared__ float s1[256];
    __shared__ float s2[256];
    const float* mr = msum + (size_t)b*256;
    float acc = bo[j];
    #pragma unroll 4
    for (int i = 0; i < 256; ++i) acc = fmaf(mr[i], wo[i*256 + j], acc);
    s1[j] = acc;
    __syncthreads();
    float a1 = d1b[j];
    #pragma unroll 4
    for (int i = 0; i < 256; ++i) a1 = fmaf(s1[i], d1w[i*256 + j], a1);
    a1 = fmaxf(a1, 0.f);
    float sc1 = g1[j] * rsqrtf(v1[j] + EPS);
    a1 = a1 * sc1 + (b1[j] - m1[j] * sc1);
    s2[j] = a1;
    __syncthreads();
    if (j < 128){
        float a2 = d2b[j];
        #pragma unroll 4
        for (int i = 0; i < 256; ++i) a2 = fmaf(s2[i], d2w[i*128 + j], a2);
        a2 = fmaxf(a2, 0.f);
        float sc2 = g2[j] * rsqrtf(v2[j] + EPS);
        a2 = a2 * sc2 + (b2[j] - m2[j] * sc2);
        s1[j] = a2;
    }
    __syncthreads();
    if (j == 0){
        float a3 = d3b[0];
        for (int i = 0; i < 128; ++i) a3 = fmaf(s1[i], d3w[i], a3);
        outp[b] = sigm(a3);
    }
}

extern "C" void kernel_launch(void* const* d_in, const int* in_sizes, int n_in,
                              void* d_out, int out_size, void* d_ws, size_t ws_size,
                              hipStream_t stream)
{
    #define F(i) ((const float*)d_in[i])
    const float* x       = F(0);
    const float* conv5_w = F(1);
    const float* conv7_w = F(2);
    const float* conv9_w = F(3);
    const float* fuse_w  = F(4);
    const float* se_w1   = F(5);
    const float* se_w2   = F(6);
    const float* l1f_k   = F(7);
    const float* l1f_r   = F(8);
    const float* l1b_k   = F(9);
    const float* l1b_r   = F(10);
    const float* l2f_k   = F(11);
    const float* l2f_r   = F(12);
    const float* l2b_k   = F(13);
    const float* l2b_r   = F(14);
    const float* wq      = F(15);
    const float* wk      = F(16);
    const float* wv      = F(17);
    const float* wo      = F(18);
    const float* d1_w    = F(19);
    const float* d2_w    = F(20);
    const float* d3_w    = F(21);
    const float* conv5_b = F(22);
    const float* conv7_b = F(23);
    const float* conv9_b = F(24);
    const float* fuse_b  = F(25);
    const float* se_b1   = F(26);
    const float* se_b2   = F(27);
    const float* l1f_b   = F(28);
    const float* l1b_b   = F(29);
    const float* l2f_b   = F(30);
    const float* l2b_b   = F(31);
    const float* bq      = F(32);
    const float* bk      = F(33);
    const float* bv      = F(34);
    const float* bo      = F(35);
    const float* d1_b    = F(36);
    const float* d2_b    = F(37);
    const float* d3_b    = F(38);
    const float* bn5_g = F(39), *bn5_b = F(40), *bn5_m = F(41), *bn5_v = F(42);
    const float* bn7_g = F(43), *bn7_b = F(44), *bn7_m = F(45), *bn7_v = F(46);
    const float* bn9_g = F(47), *bn9_b = F(48), *bn9_m = F(49), *bn9_v = F(50);
    const float* bnl1_g = F(51), *bnl1_b = F(52), *bnl1_m = F(53), *bnl1_v = F(54);
    const float* bnl2_g = F(55), *bnl2_b = F(56), *bnl2_m = F(57), *bnl2_v = F(58);
    const float* bnd1_g = F(59), *bnd1_b = F(60), *bnd1_m = F(61), *bnd1_v = F(62);
    const float* bnd2_g = F(63), *bnd2_b = F(64), *bnd2_m = F(65), *bnd2_v = F(66);
    #undef F

    float* ws = (float*)d_ws;
    // float-slot layout (budget 37,748,736 floats = 151 MB, same as proven round-2 usage):
    // concat [0, 12582912)            fp32 [65536,192]  (dead after fuse)
    // fused  [12582912, 20971520)     fp32 [65536,128]  (dead after l1 xp gemms)
    // xp1f   [0, 8388608)             bf16 [65536,512]  (concat region)
    // xp1b   [20971520, 29360128)     bf16 [65536,512]
    // l1out  [29360128, 37748736)     bf16 [65536,256]
    // xp2f   [0, 4194304)             bf16 [65536,256]
    // xp2b   [4194304, 8388608)       bf16 [65536,256]
    // l2out  [8388608, 12582912)      bf16 [65536,128]
    // qb     [12582912, 20971520)     bf16 [65536,256]  (fused region)
    // kb     [0, 8388608)             bf16 [65536,256]  (xp2 region, dead after lstm2)
    // vb     [20971520, 29360128)     bf16 [512,8,32,128] (xp1b region)
    // msum   [29360128, 29360128+131072) fp32 [512,256] (l1out region, dead after qkv gemms)
    float* concat = ws;
    float* fused  = ws + 12582912;
    unsigned short* xp1f  = (unsigned short*)(ws);
    unsigned short* xp1b  = (unsigned short*)(ws + 20971520);
    unsigned short* l1out = (unsigned short*)(ws + 29360128);
    unsigned short* xp2f  = (unsigned short*)(ws);
    unsigned short* xp2b  = (unsigned short*)(ws + 4194304);
    unsigned short* l2out = (unsigned short*)(ws + 8388608);
    unsigned short* qbuf  = (unsigned short*)(ws + 12582912);
    unsigned short* kbuf  = (unsigned short*)(ws);
    unsigned short* vbuf  = (unsigned short*)(ws + 20971520);
    float* msum   = ws + 29360128;
    float* outp   = (float*)d_out;

    conv_block_v2<5><<<dim3(512,4), dim3(256), 0, stream>>>(
        x, conv5_w, conv5_b, bn5_g, bn5_b, bn5_m, bn5_v, concat, 0);
    conv_block_v2<7><<<dim3(512,4), dim3(256), 0, stream>>>(
        x, conv7_w, conv7_b, bn7_g, bn7_b, bn7_m, bn7_v, concat, 64);
    conv_block_v2<9><<<dim3(512,4), dim3(256), 0, stream>>>(
        x, conv9_w, conv9_b, bn9_g, bn9_b, bn9_m, bn9_v, concat, 128);

    fuse_v2<<<dim3(4096), dim3(256), 0, stream>>>(concat, fuse_w, fuse_b, fused);
    se_kernel<<<dim3(512), dim3(128), 0, stream>>>(fused, se_w1, se_b1, se_w2, se_b2);

    // BiLSTM 1
    xp_gemm<128,false,0><<<dim3(512,4), dim3(256), 0, stream>>>(fused, l1f_k, l1f_b, xp1f, 512);
    xp_gemm<128,false,0><<<dim3(512,4), dim3(256), 0, stream>>>(fused, l1b_k, l1b_b, xp1b, 512);
    lstm_rec<128,true><<<dim3(128,2), dim3(512), 0, stream>>>(
        xp1f, xp1b, l1f_r, l1b_r, bnl1_g, bnl1_b, bnl1_m, bnl1_v, l1out, 0);

    // BiLSTM 2
    xp_gemm<256,true,0><<<dim3(512,2), dim3(256), 0, stream>>>(l1out, l2f_k, l2f_b, xp2f, 256);
    xp_gemm<256,true,0><<<dim3(512,2), dim3(256), 0, stream>>>(l1out, l2b_k, l2b_b, xp2b, 256);
    lstm_rec<64,true><<<dim3(128,2), dim3(512), 0, stream>>>(
        xp2f, xp2b, l2f_r, l2b_r, bnl2_g, bnl2_b, bnl2_m, bnl2_v, l2out, 0);

    // QKV projections (bf16 MFMA GEMMs); V written per-head-transposed
    xp_gemm<128,true,0><<<dim3(512,2), dim3(256), 0, stream>>>(l2out, wq, bq, qbuf, 256);
    xp_gemm<128,true,0><<<dim3(512,2), dim3(256), 0, stream>>>(l2out, wk, bk, kbuf, 256);
    xp_gemm<128,true,1><<<dim3(512,2), dim3(256), 0, stream>>>(l2out, wv, bv, vbuf, 256);

    // MFMA attention + T-mean
    attn_kernel<<<dim3(512,8), dim3(256), 0, stream>>>(qbuf, kbuf, vbuf, msum);

    // wo + dense head
    head_kernel<<<dim3(512), dim3(256), 0, stream>>>(
        msum, wo, bo,
        d1_w, d1_b, bnd1_g, bnd1_b, bnd1_m, bnd1_v,
        d2_w, d2_b, bnd2_g, bnd2_b, bnd2_m, bnd2_v,
        d3_w, d3_b, outp);

    (void)in_sizes; (void)n_in; (void)out_size; (void)ws_size;
}

// Round 5
// 716.329 us; speedup vs baseline: 10.2123x; 1.4333x over previous
//
#include <hip/hip_runtime.h>

#define EPS 1e-3f

typedef __attribute__((ext_vector_type(8))) short bf16x8;
typedef __attribute__((ext_vector_type(4))) float f32x4;

__device__ __forceinline__ float sigm(float x){ return 1.0f/(1.0f + __expf(-x)); }
__device__ __forceinline__ float tanhfast(float x){ return 1.0f - 2.0f/(1.0f + __expf(2.0f*x)); }

__device__ __forceinline__ unsigned short f2b(float f){
    union { float f; unsigned u; } v; v.f = f;
    unsigned r = v.u + 0x7FFFu + ((v.u >> 16) & 1u);
    return (unsigned short)(r >> 16);
}
__device__ __forceinline__ float b2f(unsigned short h){
    union { unsigned u; float f; } v; v.u = ((unsigned)h) << 16; return v.f;
}

// ---------------- prep: x fp32 [512,256,78] -> bf16 zero-padded [512,264,96] ----------------
__global__ void __launch_bounds__(256)
prep_x(const float* __restrict__ x, unsigned short* __restrict__ xbf)
{
    const int b = blockIdx.x;
    const float* xs = x + (size_t)b*256*78;
    unsigned short* xd = xbf + (size_t)b*264*96;
    for (int p = threadIdx.x; p < 264*48; p += 256){
        int row = p / 48;
        int cp  = (p - row*48) * 2;
        int t   = row - 4;
        unsigned short v0 = 0, v1 = 0;
        if (t >= 0 && t < 256){
            if (cp   < 78) v0 = f2b(xs[t*78 + cp]);
            if (cp+1 < 78) v1 = f2b(xs[t*78 + cp + 1]);
        }
        *(unsigned int*)(xd + row*96 + cp) = (unsigned)v0 | ((unsigned)v1 << 16);
    }
}

// ---------------- prep: unified conv weights -> bf16 B-fragment layout [27][12][512] ----------------
// wcat[k][ci][co]: co<64 -> conv5 tap k-2; co<128 -> conv7 tap k-1; else conv9 tap k. ci>=78 -> 0.
// frag slot layout: [kcs][nt][l15*32 + lg*8 + e] = wcat[k][cs*32+lg*8+e][nt*16+l15]
__global__ void __launch_bounds__(256)
prep_w(const float* __restrict__ w5, const float* __restrict__ w7, const float* __restrict__ w9,
       unsigned short* __restrict__ wfrag)
{
    int g = blockIdx.x*256 + threadIdx.x;
    if (g >= 27*12*64) return;
    union { unsigned short s[8]; uint4 v; } u;
    int base = g * 8;
    #pragma unroll
    for (int e = 0; e < 8; ++e){
        int lin  = base + e;
        int slot = lin & 511;
        int fi   = lin >> 9;
        int nt   = fi % 12, kcs = fi / 12;
        int k    = kcs / 3, cs = kcs - k*3;
        int l15  = slot >> 5, r = slot & 31;
        int lg   = r >> 3, ee = r & 7;
        int ci   = cs*32 + lg*8 + ee;
        int co   = nt*16 + l15;
        float val = 0.f;
        if (ci < 78){
            if (co < 64){
                int kk = k - 2;
                if (kk >= 0 && kk < 5) val = w5[(kk*78 + ci)*64 + co];
            } else if (co < 128){
                int kk = k - 1;
                if (kk >= 0 && kk < 7) val = w7[(kk*78 + ci)*64 + (co - 64)];
            } else {
                val = w9[(k*78 + ci)*64 + (co - 128)];
            }
        }
        u.s[e] = f2b(val);
    }
    *(uint4*)(wfrag + base) = u.v;
}

// ---------------- prep: fold conv bias + BN into biascat/scale/shift[192] ----------------
__global__ void prep_ss(const float* b5, const float* b7, const float* b9,
                        const float* g5, const float* be5, const float* m5, const float* v5,
                        const float* g7, const float* be7, const float* m7, const float* v7,
                        const float* g9, const float* be9, const float* m9, const float* v9,
                        float* __restrict__ biascat, float* __restrict__ scale, float* __restrict__ shift)
{
    int c = threadIdx.x;
    if (c >= 192) return;
    float bv, g, be, m, v;
    if (c < 64){        bv=b5[c];      g=g5[c];      be=be5[c];      m=m5[c];      v=v5[c]; }
    else if (c < 128){  int i=c-64;  bv=b7[i]; g=g7[i]; be=be7[i]; m=m7[i]; v=v7[i]; }
    else {              int i=c-128; bv=b9[i]; g=g9[i]; be=be9[i]; m=m9[i]; v=v9[i]; }
    float s = g * rsqrtf(v + EPS);
    biascat[c] = bv;
    scale[c]   = s;
    shift[c]   = be - m*s;
}

// ---------------- fused 3-conv MFMA GEMM + relu + BN + maxpool2 -> concat [512,128,192] ----------------
// Grid (512, 4). Block 256 = 4 waves; wave wv owns n-tiles wv*3..wv*3+2 (48 cols), all 4 m-tiles (64 rows).
__global__ void __launch_bounds__(256)
conv_mfma(const unsigned short* __restrict__ xbf,    // [512,264,96]
          const unsigned short* __restrict__ wfrag,  // [27][12][512]
          const float* __restrict__ biascat, const float* __restrict__ scale,
          const float* __restrict__ shift,
          float* __restrict__ out)                   // [512,128,192]
{
    const int b = blockIdx.x, tile = blockIdx.y;
    const int tid = threadIdx.x, lane = tid & 63, wv = tid >> 6;
    const int l15 = lane & 15, lg = lane >> 4;
    const int nt0 = wv * 3;
    const int t0  = tile * 64;

    f32x4 acc[4][3];
    #pragma unroll
    for (int nt = 0; nt < 3; ++nt){
        float bv = biascat[(nt0 + nt)*16 + l15];
        #pragma unroll
        for (int mt = 0; mt < 4; ++mt)
            acc[mt][nt] = (f32x4){bv, bv, bv, bv};
    }

    const unsigned short* xb = xbf + ((size_t)b*264 + t0 + l15)*96 + lg*8;
    const unsigned short* wb = wfrag + (size_t)nt0*512 + l15*32 + lg*8;

    for (int k = 0; k < 9; ++k){
        #pragma unroll
        for (int cs = 0; cs < 3; ++cs){
            bf16x8 A[4], Bf[3];
            #pragma unroll
            for (int mt = 0; mt < 4; ++mt)
                A[mt] = *(const bf16x8*)(xb + (size_t)(k + mt*16)*96 + cs*32);
            #pragma unroll
            for (int nt = 0; nt < 3; ++nt)
                Bf[nt] = *(const bf16x8*)(wb + (size_t)((k*3 + cs)*12 + nt)*512);
            #pragma unroll
            for (int mt = 0; mt < 4; ++mt)
                #pragma unroll
                for (int nt = 0; nt < 3; ++nt)
                    acc[mt][nt] = __builtin_amdgcn_mfma_f32_16x16x32_bf16(A[mt], Bf[nt], acc[mt][nt], 0, 0, 0);
        }
    }

    #pragma unroll
    for (int nt = 0; nt < 3; ++nt){
        int col = (nt0 + nt)*16 + l15;
        float s = scale[col], sh = shift[col];
        #pragma unroll
        for (int mt = 0; mt < 4; ++mt){
            float v0 = fmaxf(acc[mt][nt][0], 0.f)*s + sh;
            float v1 = fmaxf(acc[mt][nt][1], 0.f)*s + sh;
            float v2 = fmaxf(acc[mt][nt][2], 0.f)*s + sh;
            float v3 = fmaxf(acc[mt][nt][3], 0.f)*s + sh;
            int tb = tile*32 + mt*8 + lg*2;
            out[((size_t)b*128 + tb    )*192 + col] = fmaxf(v0, v1);
            out[((size_t)b*128 + tb + 1)*192 + col] = fmaxf(v2, v3);
        }
    }
}

// ---------------- 1x1 fuse conv ----------------
__global__ void __launch_bounds__(256)
fuse_v2(const float* __restrict__ in,
        const float* __restrict__ w,
        const float* __restrict__ bias,
        float* __restrict__ out)
{
    __shared__ float xl[16][192];
    const int tid = threadIdx.x;
    const size_t row0 = (size_t)blockIdx.x * 16;

    {
        const float4* ip = (const float4*)(in + row0*192);
        float4* xp = (float4*)&xl[0][0];
        #pragma unroll
        for (int idx = tid; idx < 768; idx += 256) xp[idx] = ip[idx];
    }
    __syncthreads();

    const int co = tid & 127;
    const int rg = tid >> 7;
    float acc[8];
    {
        float bv = bias[co];
        #pragma unroll
        for (int r = 0; r < 8; ++r) acc[r] = bv;
    }

    for (int ci4 = 0; ci4 < 192; ci4 += 4){
        float wv0 = w[(ci4+0)*128 + co];
        float wv1 = w[(ci4+1)*128 + co];
        float wv2 = w[(ci4+2)*128 + co];
        float wv3 = w[(ci4+3)*128 + co];
        #pragma unroll
        for (int r = 0; r < 8; ++r){
            const float4 xr = *(const float4*)&xl[rg*8 + r][ci4];
            acc[r] = fmaf(xr.x, wv0, acc[r]);
            acc[r] = fmaf(xr.y, wv1, acc[r]);
            acc[r] = fmaf(xr.z, wv2, acc[r]);
            acc[r] = fmaf(xr.w, wv3, acc[r]);
        }
    }
    #pragma unroll
    for (int r = 0; r < 8; ++r)
        out[(row0 + rg*8 + r)*128 + co] = acc[r];
}

// ---------------- SE ----------------
__global__ void se_kernel(float* __restrict__ fused,
                          const float* __restrict__ w1, const float* __restrict__ b1,
                          const float* __restrict__ w2, const float* __restrict__ b2)
{
    int b = blockIdx.x, c = threadIdx.x;
    __shared__ float sv[128];
    __shared__ float rv[8];
    float* fp = fused + (size_t)b*128*128 + c;
    float acc = 0.f;
    for (int t = 0; t < 128; ++t) acc += fp[t*128];
    sv[c] = acc * (1.f/128.f);
    __syncthreads();
    if (c < 8){
        float r = b1[c];
        for (int i = 0; i < 128; ++i) r = fmaf(sv[i], w1[i*8 + c], r);
        rv[c] = fmaxf(r, 0.f);
    }
    __syncthreads();
    float e = b2[c];
    #pragma unroll
    for (int j = 0; j < 8; ++j) e = fmaf(rv[j], w2[j*128 + c], e);
    e = sigm(e);
    for (int t = 0; t < 128; ++t) fp[t*128] *= e;
}

// ---------------- xp GEMM: out[M,N] = A[M,K] @ W[K,N] + bias, bf16 out ----------------
template<int K, bool ABF16, int OUTMODE>
__global__ void __launch_bounds__(256)
xp_gemm(const void* __restrict__ Av, const float* __restrict__ W,
        const float* __restrict__ bias, unsigned short* __restrict__ outp, int N)
{
    __shared__ unsigned short Asm[128][40];
    __shared__ unsigned short Bsm[8][64][8];

    const int tid  = threadIdx.x;
    const int lane = tid & 63;
    const int wv   = tid >> 6;
    const int wm   = wv & 1;
    const int wn   = wv >> 1;
    const size_t m0 = (size_t)blockIdx.x * 128;
    const int n0   = blockIdx.y * 128;

    f32x4 acc[4][4];
    #pragma unroll
    for (int nt = 0; nt < 4; ++nt){
        float bv = bias[n0 + wn*64 + nt*16 + (lane & 15)];
        #pragma unroll
        for (int mt = 0; mt < 4; ++mt)
            acc[mt][nt] = (f32x4){bv, bv, bv, bv};
    }

    const int bn = tid & 127;
    const int bg = tid >> 7;

    for (int k0 = 0; k0 < K; k0 += 32){
        __syncthreads();
        if constexpr (!ABF16){
            const float* Ag = (const float*)Av;
            #pragma unroll
            for (int i = 0; i < 2; ++i){
                int g = tid + i*256;
                int r = g >> 2, c8 = g & 3;
                float4 d0 = *(const float4*)(Ag + (m0 + r)*K + k0 + c8*8);
                float4 d1 = *(const float4*)(Ag + (m0 + r)*K + k0 + c8*8 + 4);
                union { unsigned short s[8]; uint4 v; } u;
                u.s[0]=f2b(d0.x); u.s[1]=f2b(d0.y); u.s[2]=f2b(d0.z); u.s[3]=f2b(d0.w);
                u.s[4]=f2b(d1.x); u.s[5]=f2b(d1.y); u.s[6]=f2b(d1.z); u.s[7]=f2b(d1.w);
                *(uint4*)&Asm[r][c8*8] = u.v;
            }
        } else {
            const unsigned short* Ag = (const unsigned short*)Av;
            #pragma unroll
            for (int i = 0; i < 2; ++i){
                int g = tid + i*256;
                int r = g >> 2, c8 = g & 3;
                uint4 d = *(const uint4*)(Ag + (m0 + r)*K + k0 + c8*8);
                *(uint4*)&Asm[r][c8*8] = d;
            }
        }
        {
            union { unsigned short s[8]; uint4 v; } u0, u1;
            #pragma unroll
            for (int q = 0; q < 8; ++q){
                u0.s[q] = f2b(W[(size_t)(k0 + bg*16 + q)*N + n0 + bn]);
                u1.s[q] = f2b(W[(size_t)(k0 + bg*16 + 8 + q)*N + n0 + bn]);
            }
            int nt = bn >> 4, lo = bn & 15;
            *(uint4*)&Bsm[nt][lo + 16*(2*bg)][0]   = u0.v;
            *(uint4*)&Bsm[nt][lo + 16*(2*bg+1)][0] = u1.v;
        }
        __syncthreads();

        bf16x8 af[4], bfr[4];
        #pragma unroll
        for (int mt = 0; mt < 4; ++mt)
            af[mt] = *(const bf16x8*)&Asm[wm*64 + mt*16 + (lane & 15)][(lane >> 4)*8];
        #pragma unroll
        for (int nt = 0; nt < 4; ++nt)
            bfr[nt] = *(const bf16x8*)&Bsm[wn*4 + nt][lane][0];
        #pragma unroll
        for (int mt = 0; mt < 4; ++mt)
            #pragma unroll
            for (int nt = 0; nt < 4; ++nt)
                acc[mt][nt] = __builtin_amdgcn_mfma_f32_16x16x32_bf16(af[mt], bfr[nt], acc[mt][nt], 0, 0, 0);
    }

    #pragma unroll
    for (int mt = 0; mt < 4; ++mt)
        #pragma unroll
        for (int nt = 0; nt < 4; ++nt)
            #pragma unroll
            for (int r = 0; r < 4; ++r){
                size_t row = m0 + wm*64 + mt*16 + (lane >> 4)*4 + r;
                int    col = n0 + wn*64 + nt*16 + (lane & 15);
                if constexpr (OUTMODE == 0){
                    outp[row*N + col] = f2b(acc[mt][nt][r]);
                } else {
                    size_t off = ((size_t)((row >> 7)*8 + (col >> 5))*32 + (col & 31))*128 + (row & 127);
                    outp[off] = f2b(acc[mt][nt][r]);
                }
            }
}

// ---------------- LSTM recurrence: z_t = xp_t + h_{t-1} @ R; R in VGPR frags ----------------
template<int U, bool OUT_BF16>
__global__ void __launch_bounds__(512)
lstm_rec(const unsigned short* __restrict__ xpf, const unsigned short* __restrict__ xpb,
         const float* __restrict__ Rf, const float* __restrict__ Rb,
         const float* __restrict__ bng, const float* __restrict__ bnb,
         const float* __restrict__ bnm, const float* __restrict__ bnv,
         void* __restrict__ outv, int dir_param)
{
    constexpr int Z   = 4*U;
    constexpr int KT  = U/32;
    constexpr int NTW = Z/128;
    constexpr int HP  = U + 8;

    __shared__ unsigned short h_lds[16][HP];
    __shared__ float z_lds[4][Z];

    const int tid  = threadIdx.x;
    const int lane = tid & 63;
    const int wv   = tid >> 6;
    const int dir  = (gridDim.y == 2) ? (int)blockIdx.y : dir_param;
    const int b0   = blockIdx.x * 4;
    const int ncol0 = wv * (Z/8);

    const unsigned short* xp = dir ? xpb : xpf;
    const float* Rg = dir ? Rb : Rf;

    for (int i = tid; i < 16*HP; i += 512) ((unsigned short*)h_lds)[i] = 0;

    bf16x8 rf[KT][NTW];
    {
        const int kb = (lane >> 4) * 8;
        const int nc = lane & 15;
        #pragma unroll
        for (int kt = 0; kt < KT; ++kt)
            #pragma unroll
            for (int nt = 0; nt < NTW; ++nt){
                union { unsigned short s[8]; bf16x8 v; } u;
                #pragma unroll
                for (int e = 0; e < 8; ++e)
                    u.s[e] = f2b(Rg[(size_t)(kt*32 + kb + e)*Z + ncol0 + nt*16 + nc]);
                rf[kt][nt] = u.v;
            }
    }

    const int u_  = tid % U;
    const int r_  = tid / U;
    const bool gate = (tid < 4*U);
    float c_ = 0.f;
    float bns = 0.f, bnsh = 0.f;
    const int ch = dir*U + u_;
    if (gate){
        bns  = bng[ch] * rsqrtf(bnv[ch] + EPS);
        bnsh = bnb[ch] - bnm[ch]*bns;
    }
    __syncthreads();

    for (int ts = 0; ts < 128; ++ts){
        const int t = dir ? 127 - ts : ts;
        unsigned short xq0=0,xq1=0,xq2=0,xq3=0;
        if (gate){
            const unsigned short* xr = xp + ((size_t)(b0 + r_)*128 + t)*Z + u_;
            xq0 = xr[0]; xq1 = xr[U]; xq2 = xr[2*U]; xq3 = xr[3*U];
        }
        bf16x8 af[KT];
        #pragma unroll
        for (int kt = 0; kt < KT; ++kt)
            af[kt] = *(const bf16x8*)&h_lds[lane & 15][kt*32 + (lane >> 4)*8];
        f32x4 acc[NTW];
        #pragma unroll
        for (int nt = 0; nt < NTW; ++nt) acc[nt] = (f32x4){0.f,0.f,0.f,0.f};
        #pragma unroll
        for (int kt = 0; kt < KT; ++kt)
            #pragma unroll
            for (int nt = 0; nt < NTW; ++nt)
                acc[nt] = __builtin_amdgcn_mfma_f32_16x16x32_bf16(af[kt], rf[kt][nt], acc[nt], 0, 0, 0);
        if ((lane >> 4) == 0){
            #pragma unroll
            for (int nt = 0; nt < NTW; ++nt)
                #pragma unroll
                for (int r = 0; r < 4; ++r)
                    z_lds[r][ncol0 + nt*16 + (lane & 15)] = acc[nt][r];
        }
        __syncthreads();
        if (gate){
            float z0 = z_lds[r_][u_      ] + b2f(xq0);
            float z1 = z_lds[r_][u_ +  U ] + b2f(xq1);
            float z2 = z_lds[r_][u_ + 2*U] + b2f(xq2);
            float z3 = z_lds[r_][u_ + 3*U] + b2f(xq3);
            float iv = sigm(z0), fv = sigm(z1), gv = tanhfast(z2), ov = sigm(z3);
            c_ = fv*c_ + iv*gv;
            float h = ov * tanhfast(c_);
            h_lds[r_][u_] = f2b(h);
            float hb = fmaf(h, bns, bnsh);
            size_t oidx = ((size_t)(b0 + r_)*128 + t)*(size_t)(2*U) + ch;
            if constexpr (OUT_BF16) ((unsigned short*)outv)[oidx] = f2b(hb);
            else                    ((float*)outv)[oidx] = hb;
        }
        __syncthreads();
    }
}

// ---------------- MFMA attention per (b, head): S=QK^T, softmax, PV, T-mean ----------------
__global__ void __launch_bounds__(256)
attn_kernel(const unsigned short* __restrict__ qb,
            const unsigned short* __restrict__ kb,
            const unsigned short* __restrict__ vb,
            float* __restrict__ msum)
{
    __shared__ unsigned short p_lds[128][136];
    __shared__ float red[4][2][16];

    const int b  = blockIdx.x, hd = blockIdx.y;
    const int tid = threadIdx.x, lane = tid & 63, wv = tid >> 6;
    const int m0 = wv * 32;
    const int l15 = lane & 15, lg = lane >> 4;

    bf16x8 aq[2];
    #pragma unroll
    for (int mt = 0; mt < 2; ++mt)
        aq[mt] = *(const bf16x8*)(qb + ((size_t)(b*128 + m0 + mt*16 + l15))*256 + hd*32 + lg*8);

    bf16x8 bk[8];
    #pragma unroll
    for (int nt = 0; nt < 8; ++nt)
        bk[nt] = *(const bf16x8*)(kb + ((size_t)(b*128 + nt*16 + l15))*256 + hd*32 + lg*8);

    f32x4 s[2][8];
    #pragma unroll
    for (int mt = 0; mt < 2; ++mt)
        #pragma unroll
        for (int nt = 0; nt < 8; ++nt) s[mt][nt] = (f32x4){0.f,0.f,0.f,0.f};
    #pragma unroll
    for (int mt = 0; mt < 2; ++mt)
        #pragma unroll
        for (int nt = 0; nt < 8; ++nt)
            s[mt][nt] = __builtin_amdgcn_mfma_f32_16x16x32_bf16(aq[mt], bk[nt], s[mt][nt], 0, 0, 0);

    const float scale = 0.17677669529663687f;
    #pragma unroll
    for (int mt = 0; mt < 2; ++mt)
        #pragma unroll
        for (int r = 0; r < 4; ++r){
            float mx = -1e30f;
            #pragma unroll
            for (int nt = 0; nt < 8; ++nt) mx = fmaxf(mx, s[mt][nt][r]);
            #pragma unroll
            for (int msk = 1; msk < 16; msk <<= 1) mx = fmaxf(mx, __shfl_xor(mx, msk, 64));
            float pv[8], sum = 0.f;
            #pragma unroll
            for (int nt = 0; nt < 8; ++nt){
                pv[nt] = __expf((s[mt][nt][r] - mx) * scale);
                sum += pv[nt];
            }
            #pragma unroll
            for (int msk = 1; msk < 16; msk <<= 1) sum += __shfl_xor(sum, msk, 64);
            float inv = 1.f / sum;
            int row = m0 + mt*16 + lg*4 + r;
            #pragma unroll
            for (int nt = 0; nt < 8; ++nt)
                p_lds[row][nt*16 + l15] = f2b(pv[nt] * inv);
        }
    __syncthreads();

    f32x4 o[2][2];
    #pragma unroll
    for (int mt = 0; mt < 2; ++mt)
        #pragma unroll
        for (int dn = 0; dn < 2; ++dn) o[mt][dn] = (f32x4){0.f,0.f,0.f,0.f};
    bf16x8 bv[4][2];
    #pragma unroll
    for (int kt = 0; kt < 4; ++kt)
        #pragma unroll
        for (int dn = 0; dn < 2; ++dn)
            bv[kt][dn] = *(const bf16x8*)(vb + ((size_t)(b*8 + hd)*32 + dn*16 + l15)*128 + kt*32 + lg*8);
    #pragma unroll
    for (int mt = 0; mt < 2; ++mt)
        #pragma unroll
        for (int kt = 0; kt < 4; ++kt){
            bf16x8 ap = *(const bf16x8*)&p_lds[m0 + mt*16 + l15][kt*32 + lg*8];
            #pragma unroll
            for (int dn = 0; dn < 2; ++dn)
                o[mt][dn] = __builtin_amdgcn_mfma_f32_16x16x32_bf16(ap, bv[kt][dn], o[mt][dn], 0, 0, 0);
        }

    float sm[2];
    #pragma unroll
    for (int dn = 0; dn < 2; ++dn){
        float a = 0.f;
        #pragma unroll
        for (int mt = 0; mt < 2; ++mt)
            #pragma unroll
            for (int r = 0; r < 4; ++r) a += o[mt][dn][r];
        a += __shfl_xor(a, 16, 64);
        a += __shfl_xor(a, 32, 64);
        sm[dn] = a;
    }
    if (lg == 0){
        red[wv][0][l15] = sm[0];
        red[wv][1][l15] = sm[1];
    }
    __syncthreads();
    if (tid < 32){
        int dn = tid >> 4, n = tid & 15;
        float tot = red[0][dn][n] + red[1][dn][n] + red[2][dn][n] + red[3][dn][n];
        msum[(size_t)b*256 + hd*32 + dn*16 + n] = tot * (1.f/128.f);
    }
}

// ---------------- head ----------------
__global__ void __launch_bounds__(256)
head_kernel(const float* __restrict__ msum,
            const float* __restrict__ wo, const float* __restrict__ bo,
            const float* __restrict__ d1w, const float* __restrict__ d1b,
            const float* __restrict__ g1, const float* __restrict__ b1,
            const float* __restrict__ m1, const float* __restrict__ v1,
            const float* __restrict__ d2w, const float* __restrict__ d2b,
            const float* __restrict__ g2, const float* __restrict__ b2,
            const float* __restrict__ m2, const float* __restrict__ v2,
            const float* __restrict__ d3w, const float* __restrict__ d3b,
            float* __restrict__ outp)
{
    int b = blockIdx.x, j = threadIdx.x;
    __shared__ float s1[256];
    __shared__ float s2[256];
    const float* mr = msum + (size_t)b*256;
    float acc = bo[j];
    #pragma unroll 4
    for (int i = 0; i < 256; ++i) acc = fmaf(mr[i], wo[i*256 + j], acc);
    s1[j] = acc;
    __syncthreads();
    float a1 = d1b[j];
    #pragma unroll 4
    for (int i = 0; i < 256; ++i) a1 = fmaf(s1[i], d1w[i*256 + j], a1);
    a1 = fmaxf(a1, 0.f);
    float sc1 = g1[j] * rsqrtf(v1[j] + EPS);
    a1 = a1 * sc1 + (b1[j] - m1[j] * sc1);
    s2[j] = a1;
    __syncthreads();
    if (j < 128){
        float a2 = d2b[j];
        #pragma unroll 4
        for (int i = 0; i < 256; ++i) a2 = fmaf(s2[i], d2w[i*128 + j], a2);
        a2 = fmaxf(a2, 0.f);
        float sc2 = g2[j] * rsqrtf(v2[j] + EPS);
        a2 = a2 * sc2 + (b2[j] - m2[j] * sc2);
        s1[j] = a2;
    }
    __syncthreads();
    if (j == 0){
        float a3 = d3b[0];
        for (int i = 0; i < 128; ++i) a3 = fmaf(s1[i], d3w[i], a3);
        outp[b] = sigm(a3);
    }
}

extern "C" void kernel_launch(void* const* d_in, const int* in_sizes, int n_in,
                              void* d_out, int out_size, void* d_ws, size_t ws_size,
                              hipStream_t stream)
{
    #define F(i) ((const float*)d_in[i])
    const float* x       = F(0);
    const float* conv5_w = F(1);
    const float* conv7_w = F(2);
    const float* conv9_w = F(3);
    const float* fuse_w  = F(4);
    const float* se_w1   = F(5);
    const float* se_w2   = F(6);
    const float* l1f_k   = F(7);
    const float* l1f_r   = F(8);
    const float* l1b_k   = F(9);
    const float* l1b_r   = F(10);
    const float* l2f_k   = F(11);
    const float* l2f_r   = F(12);
    const float* l2b_k   = F(13);
    const float* l2b_r   = F(14);
    const float* wq      = F(15);
    const float* wk      = F(16);
    const float* wv      = F(17);
    const float* wo      = F(18);
    const float* d1_w    = F(19);
    const float* d2_w    = F(20);
    const float* d3_w    = F(21);
    const float* conv5_b = F(22);
    const float* conv7_b = F(23);
    const float* conv9_b = F(24);
    const float* fuse_b  = F(25);
    const float* se_b1   = F(26);
    const float* se_b2   = F(27);
    const float* l1f_b   = F(28);
    const float* l1b_b   = F(29);
    const float* l2f_b   = F(30);
    const float* l2b_b   = F(31);
    const float* bq      = F(32);
    const float* bk      = F(33);
    const float* bv      = F(34);
    const float* bo      = F(35);
    const float* d1_b    = F(36);
    const float* d2_b    = F(37);
    const float* d3_b    = F(38);
    const float* bn5_g = F(39), *bn5_b = F(40), *bn5_m = F(41), *bn5_v = F(42);
    const float* bn7_g = F(43), *bn7_b = F(44), *bn7_m = F(45), *bn7_v = F(46);
    const float* bn9_g = F(47), *bn9_b = F(48), *bn9_m = F(49), *bn9_v = F(50);
    const float* bnl1_g = F(51), *bnl1_b = F(52), *bnl1_m = F(53), *bnl1_v = F(54);
    const float* bnl2_g = F(55), *bnl2_b = F(56), *bnl2_m = F(57), *bnl2_v = F(58);
    const float* bnd1_g = F(59), *bnd1_b = F(60), *bnd1_m = F(61), *bnd1_v = F(62);
    const float* bnd2_g = F(63), *bnd2_b = F(64), *bnd2_m = F(65), *bnd2_v = F(66);
    #undef F

    float* ws = (float*)d_ws;
    // float-slot layout (max 37,748,736 floats = 151 MB):
    // concat [0, 12582912)            fp32 [65536,192]
    // fused  [12582912, 20971520)     fp32 [65536,128]
    // xbf    [20971520, 27607040)     bf16 [512,264,96]  (dead after conv_mfma)
    // wfrag  [27607040, 27689984)     bf16 [27][12][512] (dead after conv_mfma)
    // ss     [27689984, 27690560)     fp32 192*3        (dead after conv_mfma)
    // xp1f   [0, 8388608)             bf16 (concat region)
    // xp1b   [20971520, 29360128)     bf16 (xbf/wfrag region)
    // l1out  [29360128, 37748736)     bf16
    // xp2f   [0, 4194304)  xp2b [4194304, 8388608)  l2out [8388608, 12582912)  bf16
    // qb     [12582912, 20971520)  kb [0, 8388608)  vb [20971520, 29360128)    bf16
    // msum   [29360128, +131072)      fp32
    float* concat = ws;
    float* fused  = ws + 12582912;
    unsigned short* xbf   = (unsigned short*)(ws + 20971520);
    unsigned short* wfrag = (unsigned short*)(ws + 27607040);
    float* biascat = ws + 27689984;
    float* cscale  = ws + 27690176;
    float* cshift  = ws + 27690368;
    unsigned short* xp1f  = (unsigned short*)(ws);
    unsigned short* xp1b  = (unsigned short*)(ws + 20971520);
    unsigned short* l1out = (unsigned short*)(ws + 29360128);
    unsigned short* xp2f  = (unsigned short*)(ws);
    unsigned short* xp2b  = (unsigned short*)(ws + 4194304);
    unsigned short* l2out = (unsigned short*)(ws + 8388608);
    unsigned short* qbuf  = (unsigned short*)(ws + 12582912);
    unsigned short* kbuf  = (unsigned short*)(ws);
    unsigned short* vbuf  = (unsigned short*)(ws + 20971520);
    float* msum   = ws + 29360128;
    float* outp   = (float*)d_out;

    // conv prep + fused conv GEMM
    prep_x<<<dim3(512), dim3(256), 0, stream>>>(x, xbf);
    prep_w<<<dim3(81), dim3(256), 0, stream>>>(conv5_w, conv7_w, conv9_w, wfrag);
    prep_ss<<<dim3(1), dim3(192), 0, stream>>>(
        conv5_b, conv7_b, conv9_b,
        bn5_g, bn5_b, bn5_m, bn5_v,
        bn7_g, bn7_b, bn7_m, bn7_v,
        bn9_g, bn9_b, bn9_m, bn9_v,
        biascat, cscale, cshift);
    conv_mfma<<<dim3(512,4), dim3(256), 0, stream>>>(
        xbf, wfrag, biascat, cscale, cshift, concat);

    fuse_v2<<<dim3(4096), dim3(256), 0, stream>>>(concat, fuse_w, fuse_b, fused);
    se_kernel<<<dim3(512), dim3(128), 0, stream>>>(fused, se_w1, se_b1, se_w2, se_b2);

    // BiLSTM 1
    xp_gemm<128,false,0><<<dim3(512,4), dim3(256), 0, stream>>>(fused, l1f_k, l1f_b, xp1f, 512);
    xp_gemm<128,false,0><<<dim3(512,4), dim3(256), 0, stream>>>(fused, l1b_k, l1b_b, xp1b, 512);
    lstm_rec<128,true><<<dim3(128,2), dim3(512), 0, stream>>>(
        xp1f, xp1b, l1f_r, l1b_r, bnl1_g, bnl1_b, bnl1_m, bnl1_v, l1out, 0);

    // BiLSTM 2
    xp_gemm<256,true,0><<<dim3(512,2), dim3(256), 0, stream>>>(l1out, l2f_k, l2f_b, xp2f, 256);
    xp_gemm<256,true,0><<<dim3(512,2), dim3(256), 0, stream>>>(l1out, l2b_k, l2b_b, xp2b, 256);
    lstm_rec<64,true><<<dim3(128,2), dim3(512), 0, stream>>>(
        xp2f, xp2b, l2f_r, l2b_r, bnl2_g, bnl2_b, bnl2_m, bnl2_v, l2out, 0);

    // QKV projections; V per-head-transposed
    xp_gemm<128,true,0><<<dim3(512,2), dim3(256), 0, stream>>>(l2out, wq, bq, qbuf, 256);
    xp_gemm<128,true,0><<<dim3(512,2), dim3(256), 0, stream>>>(l2out, wk, bk, kbuf, 256);
    xp_gemm<128,true,1><<<dim3(512,2), dim3(256), 0, stream>>>(l2out, wv, bv, vbuf, 256);

    // MFMA attention + T-mean
    attn_kernel<<<dim3(512,8), dim3(256), 0, stream>>>(qbuf, kbuf, vbuf, msum);

    // wo + dense head
    head_kernel<<<dim3(512), dim3(256), 0, stream>>>(
        msum, wo, bo,
        d1_w, d1_b, bnd1_g, bnd1_b, bnd1_m, bnd1_v,
        d2_w, d2_b, bnd2_g, bnd2_b, bnd2_m, bnd2_v,
        d3_w, d3_b, outp);

    (void)in_sizes; (void)n_in; (void)out_size; (void)ws_size;
}